// Round 12
// baseline (168.422 us; speedup 1.0000x reference)
//
#include <hip/hip_runtime.h>

// ---- types ----
typedef __bf16 bf16x8 __attribute__((ext_vector_type(8)));
typedef float  f32x4  __attribute__((ext_vector_type(4)));
typedef float  f32x16 __attribute__((ext_vector_type(16)));
typedef unsigned int uint32x4 __attribute__((ext_vector_type(4)));

__device__ __forceinline__ short f2bf(float f) {
  union { float f; unsigned u; } v; v.f = f;
  unsigned r = v.u + 0x7fffu + ((v.u >> 16) & 1u);
  return (short)(r >> 16);
}

// async global->LDS (16B per lane); LDS dest must be wave-uniform base + lane*16
__device__ __forceinline__ void gl_lds16(const short* g, short* l) {
  __builtin_amdgcn_global_load_lds((const __attribute__((address_space(1))) void*)g,
                                   (__attribute__((address_space(3))) void*)l, 16, 0, 0);
}

// ---- cast x fp32 -> bf16 (vectorized) ----
__global__ __launch_bounds__(256) void cast_x_kernel(const float* __restrict__ in,
                                                     short* __restrict__ out, int n4) {
  int i = blockIdx.x * 256 + threadIdx.x;
  if (i >= n4) return;
  float4 f = reinterpret_cast<const float4*>(in)[i];
  short4 o;
  o.x = f2bf(f.x); o.y = f2bf(f.y); o.z = f2bf(f.z); o.w = f2bf(f.w);
  reinterpret_cast<short4*>(out)[i] = o;
}

// ---- transpose + cast: in[R][Cc] fp32 -> out[Cc][R] bf16 ----
__global__ __launch_bounds__(256) void transpose_cast(const float* __restrict__ in,
                                                      short* __restrict__ out, int R, int Cc) {
  __shared__ short tile[64][65];
  int bx = blockIdx.x * 64;
  int by = blockIdx.y * 64;
  int tx = threadIdx.x & 63, ty = threadIdx.x >> 6;
  #pragma unroll
  for (int i = ty; i < 64; i += 4)
    tile[i][tx] = f2bf(in[(size_t)(by + i) * Cc + bx + tx]);
  __syncthreads();
  #pragma unroll
  for (int i = ty; i < 64; i += 4)
    out[(size_t)(bx + i) * R + by + tx] = tile[tx][i];
}

// ---- GEMM1: qkv = x_bf[4096][1024] * Wqkv_t[3072][1024]^T + bqkv
//      q,k -> [B2][H16][T2048][D64] bf16 (q scaled 0.125*log2e); v -> [BH][D64][T2048]
__global__ __launch_bounds__(256) void gemm_qkv(const short* __restrict__ A,
                                                const short* __restrict__ Bt,
                                                const float* __restrict__ bias,
                                                short* __restrict__ qo,
                                                short* __restrict__ ko,
                                                short* __restrict__ vt) {
  const int K = 1024;
  __shared__ short Al[8192];   // linear [128][64]
  __shared__ short Bl[8192];
  int tid = threadIdx.x;
  int mtile = blockIdx.y * 128, ntile = blockIdx.x * 128;
  int w = tid >> 6, l = tid & 63;
  int wr = w >> 1, wc = w & 1;
  int lr = l & 15, lg = l >> 4;

  f32x4 zero4 = {0.f, 0.f, 0.f, 0.f};
  f32x4 acc[4][4];
  #pragma unroll
  for (int i = 0; i < 4; ++i)
    #pragma unroll
    for (int j = 0; j < 4; ++j) acc[i][j] = zero4;

  for (int k0 = 0; k0 < K; k0 += 64) {
    __syncthreads();
    #pragma unroll
    for (int c = 0; c < 4; ++c) {
      int idx = tid + c * 256;
      int row = idx >> 3, kc = idx & 7;
      gl_lds16(&A[(size_t)(mtile + row) * K + k0 + kc * 8], &Al[idx * 8]);
      gl_lds16(&Bt[(size_t)(ntile + row) * K + k0 + kc * 8], &Bl[idx * 8]);
    }
    __syncthreads();
    __builtin_amdgcn_s_setprio(1);
    #pragma unroll
    for (int kk = 0; kk < 2; ++kk) {
      bf16x8 af[4], bfr[4];
      #pragma unroll
      for (int i = 0; i < 4; ++i)
        af[i] = *reinterpret_cast<const bf16x8*>(&Al[(wr * 64 + i * 16 + lr) * 64 + kk * 32 + lg * 8]);
      #pragma unroll
      for (int j = 0; j < 4; ++j)
        bfr[j] = *reinterpret_cast<const bf16x8*>(&Bl[(wc * 64 + j * 16 + lr) * 64 + kk * 32 + lg * 8]);
      #pragma unroll
      for (int i = 0; i < 4; ++i)
        #pragma unroll
        for (int j = 0; j < 4; ++j)
          acc[i][j] = __builtin_amdgcn_mfma_f32_16x16x32_bf16(af[i], bfr[j], acc[i][j], 0, 0, 0);
    }
    __builtin_amdgcn_s_setprio(0);
  }

  #pragma unroll
  for (int j = 0; j < 4; ++j) {
    int n = ntile + wc * 64 + j * 16 + lr;   // 0..3071 (sec uniform per block)
    float bv = bias[n];
    int sec = n >> 10;
    int ch = n & 1023;
    int h = ch >> 6, d = ch & 63;
    if (sec == 2) {
      #pragma unroll
      for (int i = 0; i < 4; ++i) {
        int t0g = mtile + wr * 64 + i * 16 + lg * 4;
        int bb = t0g >> 11, t = t0g & 2047;
        short4 pk;
        pk.x = f2bf(acc[i][j][0] + bv);
        pk.y = f2bf(acc[i][j][1] + bv);
        pk.z = f2bf(acc[i][j][2] + bv);
        pk.w = f2bf(acc[i][j][3] + bv);
        *reinterpret_cast<short4*>(&vt[((size_t)(bb * 16 + h) * 64 + d) * 2048 + t]) = pk;
      }
    } else {
      short* dst = (sec == 0) ? qo : ko;
      // q scaled by (1/sqrt(64)) * log2(e) so attention works in exp2 domain
      float sc = (sec == 0) ? 0.18033688f : 1.0f;
      #pragma unroll
      for (int i = 0; i < 4; ++i) {
        #pragma unroll
        for (int r = 0; r < 4; ++r) {
          int m = mtile + wr * 64 + i * 16 + lg * 4 + r;
          int bb = m >> 11, t = m & 2047;
          dst[(size_t)((bb * 16 + h) * 2048 + t) * 64 + d] = f2bf((acc[i][j][r] + bv) * sc);
        }
      }
    }
  }
}

// ---- flash attention v11: paired q-tiles (j, 63-j) per block -> TWO independent
//      chains per wave sharing one K/V tile load (static ILP; prefetch rounds
//      v9-v10 showed the compiler won't hold prefetch regs). 4-wave kv-split,
//      branchless diag masks, sequential dual merge reusing the partial buffer. ----
__device__ __forceinline__ void chain_step(bf16x8 kf0, bf16x8 kf1, bf16x8 kf2, bf16x8 kf3,
                                           uint4 vr0, uint4 vr1, uint4 vr2, uint4 vr3,
                                           const bf16x8* qf,
                                           f32x16& y0, f32x16& y1,
                                           float& m, float& li,
                                           int lq, int hl, bool diag) {
  f32x16 s;
  #pragma unroll
  for (int r = 0; r < 16; ++r) s[r] = 0.f;
  s = __builtin_amdgcn_mfma_f32_32x32x16_bf16(kf0, qf[0], s, 0, 0, 0);
  s = __builtin_amdgcn_mfma_f32_32x32x16_bf16(kf1, qf[1], s, 0, 0, 0);
  s = __builtin_amdgcn_mfma_f32_32x32x16_bf16(kf2, qf[2], s, 0, 0, 0);
  s = __builtin_amdgcn_mfma_f32_32x32x16_bf16(kf3, qf[3], s, 0, 0, 0);
  // branchless causal mask (diag is wave-uniform; cndmask, no CF split)
  #pragma unroll
  for (int r = 0; r < 16; ++r) {
    int kvl = (r & 3) + 8 * (r >> 2) + 4 * hl;
    s[r] = (diag && kvl > lq) ? -1e30f : s[r];
  }
  float a0 = fmaxf(fmaxf(s[0], s[1]), fmaxf(s[2], s[3]));
  float a1 = fmaxf(fmaxf(s[4], s[5]), fmaxf(s[6], s[7]));
  float a2 = fmaxf(fmaxf(s[8], s[9]), fmaxf(s[10], s[11]));
  float a3 = fmaxf(fmaxf(s[12], s[13]), fmaxf(s[14], s[15]));
  float pm = fmaxf(fmaxf(a0, a1), fmaxf(a2, a3));
  pm = fmaxf(pm, __shfl_xor(pm, 32));
  if (!__all(pm - m <= 8.0f)) {   // defer-max: rare
    float mn = fmaxf(m, pm);
    float sc = __builtin_amdgcn_exp2f(m - mn);
    m = mn;
    li *= sc;
    #pragma unroll
    for (int r = 0; r < 16; ++r) { y0[r] *= sc; y1[r] *= sc; }
  }
  unsigned u[8];
  float rs = 0.f;
  #pragma unroll
  for (int rq = 0; rq < 4; ++rq) {
    float p0 = __builtin_amdgcn_exp2f(s[4 * rq + 0] - m);
    float p1 = __builtin_amdgcn_exp2f(s[4 * rq + 1] - m);
    float p2 = __builtin_amdgcn_exp2f(s[4 * rq + 2] - m);
    float p3 = __builtin_amdgcn_exp2f(s[4 * rq + 3] - m);
    rs += (p0 + p1) + (p2 + p3);
    asm("v_cvt_pk_bf16_f32 %0, %1, %2" : "=v"(u[rq * 2 + 0]) : "v"(p0), "v"(p1));
    asm("v_cvt_pk_bf16_f32 %0, %1, %2" : "=v"(u[rq * 2 + 1]) : "v"(p2), "v"(p3));
  }
  rs += __shfl_xor(rs, 32);
  li += rs;
  asm volatile("v_permlane32_swap_b32 %0, %1" : "+v"(u[0]), "+v"(u[2]));
  asm volatile("v_permlane32_swap_b32 %0, %1" : "+v"(u[1]), "+v"(u[3]));
  asm volatile("v_permlane32_swap_b32 %0, %1" : "+v"(u[4]), "+v"(u[6]));
  asm volatile("v_permlane32_swap_b32 %0, %1" : "+v"(u[5]), "+v"(u[7]));
  uint32x4 w0 = {u[0], u[1], u[2], u[3]};
  uint32x4 w1 = {u[4], u[5], u[6], u[7]};
  bf16x8 pa0 = __builtin_bit_cast(bf16x8, w0);
  bf16x8 pa1 = __builtin_bit_cast(bf16x8, w1);
  {
    bf16x8 vf00 = __builtin_bit_cast(bf16x8, vr0);
    bf16x8 vf01 = __builtin_bit_cast(bf16x8, vr1);
    bf16x8 vf10 = __builtin_bit_cast(bf16x8, vr2);
    bf16x8 vf11 = __builtin_bit_cast(bf16x8, vr3);
    y0 = __builtin_amdgcn_mfma_f32_32x32x16_bf16(vf00, pa0, y0, 0, 0, 0);
    y0 = __builtin_amdgcn_mfma_f32_32x32x16_bf16(vf01, pa1, y0, 0, 0, 0);
    y1 = __builtin_amdgcn_mfma_f32_32x32x16_bf16(vf10, pa0, y1, 0, 0, 0);
    y1 = __builtin_amdgcn_mfma_f32_32x32x16_bf16(vf11, pa1, y1, 0, 0, 0);
  }
}

__global__ __launch_bounds__(256, 3) void attn_kernel(const short* __restrict__ q,
                                                      const short* __restrict__ k,
                                                      const short* __restrict__ vt,
                                                      short* __restrict__ y) {
  __shared__ float partL[3][8][64][4];   // 24 KB, reused for both merges
  __shared__ float stm[2][4][32], stl[2][4][32];
  const int bid = blockIdx.x;
  const int xcd = bid & 7;
  const int p = bid >> 3;
  const int j = p & 31;                    // lo q-tile
  const int bh = xcd * 4 + (p >> 5);       // 4 bh per XCD -> K/V L2-resident
  const int thi = 63 - j;                  // hi q-tile
  const int tid = threadIdx.x;
  const int w = tid >> 6;                  // kv-split index 0..3
  const int l = tid & 63;
  const int lq = l & 31, hl = l >> 5;
  const short* qb = q + (size_t)bh * 131072;
  const short* kb = k + (size_t)bh * 131072;
  const short* vb = vt + (size_t)bh * 131072;   // [64][2048]

  // Q B-frags for both chains
  bf16x8 qfA[4], qfB[4];
  {
    const short* qpA = &qb[(size_t)(32 * thi + lq) * 64 + hl * 8];
    const short* qpB = &qb[(size_t)(32 * j + lq) * 64 + hl * 8];
    #pragma unroll
    for (int ks = 0; ks < 4; ++ks) {
      qfA[ks] = *reinterpret_cast<const bf16x8*>(qpA + ks * 16);
      qfB[ks] = *reinterpret_cast<const bf16x8*>(qpB + ks * 16);
    }
  }

  f32x16 yA0, yA1, yB0, yB1;
  #pragma unroll
  for (int r = 0; r < 16; ++r) { yA0[r] = 0.f; yA1[r] = 0.f; yB0[r] = 0.f; yB1[r] = 0.f; }
  float mA = -1e30f, liA = 0.f, mB = -1e30f, liB = 0.f;

  const short* kb0 = kb + (size_t)lq * 64 + hl * 8;   // + tile*2048
  const short* vb0 = vb + (size_t)lq * 2048 + hl * 8; // + tile*32

  int tile = w;
  // phase 1: tiles <= j -> both chains share the K/V load
  for (; tile <= j; tile += 4) {
    const short* kp = kb0 + (size_t)tile * 2048;
    const short* vp = vb0 + tile * 32;
    bf16x8 kf0 = *reinterpret_cast<const bf16x8*>(kp);
    bf16x8 kf1 = *reinterpret_cast<const bf16x8*>(kp + 16);
    bf16x8 kf2 = *reinterpret_cast<const bf16x8*>(kp + 32);
    bf16x8 kf3 = *reinterpret_cast<const bf16x8*>(kp + 48);
    uint4 vr0 = *reinterpret_cast<const uint4*>(vp);
    uint4 vr1 = *reinterpret_cast<const uint4*>(vp + 16);
    uint4 vr2 = *reinterpret_cast<const uint4*>(vp + 32 * 2048);
    uint4 vr3 = *reinterpret_cast<const uint4*>(vp + 32 * 2048 + 16);
    chain_step(kf0, kf1, kf2, kf3, vr0, vr1, vr2, vr3, qfA,
               yA0, yA1, mA, liA, lq, hl, false);
    chain_step(kf0, kf1, kf2, kf3, vr0, vr1, vr2, vr3, qfB,
               yB0, yB1, mB, liB, lq, hl, tile == j);
  }
  // phase 2: chain A only
  for (; tile <= thi; tile += 4) {
    const short* kp = kb0 + (size_t)tile * 2048;
    const short* vp = vb0 + tile * 32;
    bf16x8 kf0 = *reinterpret_cast<const bf16x8*>(kp);
    bf16x8 kf1 = *reinterpret_cast<const bf16x8*>(kp + 16);
    bf16x8 kf2 = *reinterpret_cast<const bf16x8*>(kp + 32);
    bf16x8 kf3 = *reinterpret_cast<const bf16x8*>(kp + 48);
    uint4 vr0 = *reinterpret_cast<const uint4*>(vp);
    uint4 vr1 = *reinterpret_cast<const uint4*>(vp + 16);
    uint4 vr2 = *reinterpret_cast<const uint4*>(vp + 32 * 2048);
    uint4 vr3 = *reinterpret_cast<const uint4*>(vp + 32 * 2048 + 16);
    chain_step(kf0, kf1, kf2, kf3, vr0, vr1, vr2, vr3, qfA,
               yA0, yA1, mA, liA, lq, hl, tile == thi);
  }

  // ---- dual merge (A then B, partL reused) ----
  if (hl == 0) {
    stm[0][w][lq] = mA; stl[0][w][lq] = liA;
    stm[1][w][lq] = mB; stl[1][w][lq] = liB;
  }
  __syncthreads();
  int b_ = bh >> 4, h_ = bh & 15;

#define MERGE_OUT(CI, MI, Y0, Y1, QT) do {                                           \
    float m0_ = stm[CI][0][lq], m1_ = stm[CI][1][lq];                                \
    float m2_ = stm[CI][2][lq], m3_ = stm[CI][3][lq];                                \
    float M_ = fmaxf(fmaxf(m0_, m1_), fmaxf(m2_, m3_));                              \
    float L_ = stl[CI][0][lq] * __builtin_amdgcn_exp2f(m0_ - M_) +                   \
               stl[CI][1][lq] * __builtin_amdgcn_exp2f(m1_ - M_) +                   \
               stl[CI][2][lq] * __builtin_amdgcn_exp2f(m2_ - M_) +                   \
               stl[CI][3][lq] * __builtin_amdgcn_exp2f(m3_ - M_);                    \
    float sc_ = __builtin_amdgcn_exp2f((MI) - M_);                                   \
    _Pragma("unroll")                                                                \
    for (int r = 0; r < 16; ++r) { (Y0)[r] *= sc_; (Y1)[r] *= sc_; }                 \
    if (w > 0) {                                                                     \
      _Pragma("unroll")                                                              \
      for (int c = 0; c < 4; ++c) {                                                  \
        f32x4 v0_ = {(Y0)[4 * c + 0], (Y0)[4 * c + 1], (Y0)[4 * c + 2], (Y0)[4 * c + 3]}; \
        f32x4 v1_ = {(Y1)[4 * c + 0], (Y1)[4 * c + 1], (Y1)[4 * c + 2], (Y1)[4 * c + 3]}; \
        *reinterpret_cast<f32x4*>(&partL[w - 1][c][l][0]) = v0_;                     \
        *reinterpret_cast<f32x4*>(&partL[w - 1][c + 4][l][0]) = v1_;                 \
      }                                                                              \
    }                                                                                \
    __syncthreads();                                                                 \
    if (w == 0) {                                                                    \
      _Pragma("unroll")                                                              \
      for (int o = 0; o < 3; ++o)                                                    \
        _Pragma("unroll")                                                            \
        for (int c = 0; c < 4; ++c) {                                                \
          f32x4 v0_ = *reinterpret_cast<const f32x4*>(&partL[o][c][l][0]);           \
          f32x4 v1_ = *reinterpret_cast<const f32x4*>(&partL[o][c + 4][l][0]);       \
          _Pragma("unroll")                                                          \
          for (int r = 0; r < 4; ++r) { (Y0)[4 * c + r] += v0_[r]; (Y1)[4 * c + r] += v1_[r]; } \
        }                                                                            \
      float inv_ = 1.0f / L_;                                                        \
      short* yrow_ = &y[(size_t)(b_ * 2048 + 32 * (QT) + lq) * 1024 + h_ * 64];      \
      _Pragma("unroll")                                                              \
      for (int dt = 0; dt < 2; ++dt) {                                               \
        const f32x16& yy_ = dt ? (Y1) : (Y0);                                        \
        _Pragma("unroll")                                                            \
        for (int rq = 0; rq < 4; ++rq) {                                             \
          int d0_ = dt * 32 + 8 * rq + 4 * hl;                                       \
          uint2 pk_;                                                                 \
          pk_.x = (unsigned)(unsigned short)f2bf(yy_[4 * rq + 0] * inv_) |           \
                  ((unsigned)(unsigned short)f2bf(yy_[4 * rq + 1] * inv_) << 16);    \
          pk_.y = (unsigned)(unsigned short)f2bf(yy_[4 * rq + 2] * inv_) |           \
                  ((unsigned)(unsigned short)f2bf(yy_[4 * rq + 3] * inv_) << 16);    \
          *reinterpret_cast<uint2*>(yrow_ + d0_) = pk_;                              \
        }                                                                            \
      }                                                                              \
    }                                                                                \
  } while (0)

  MERGE_OUT(0, mA, yA0, yA1, thi);
  __syncthreads();   // protect partL reuse
  MERGE_OUT(1, mB, yB0, yB1, j);
#undef MERGE_OUT
}

// ---- GEMM3: out fp32 = y_bf[4096][1024] * Wproj_t[1024][1024]^T + bproj ----
__global__ __launch_bounds__(256) void gemm_proj(const short* __restrict__ A,
                                                 const short* __restrict__ Bt,
                                                 const float* __restrict__ bias,
                                                 float* __restrict__ out) {
  const int K = 1024;
  __shared__ short Al[8192];
  __shared__ short Bl[8192];
  int tid = threadIdx.x;
  int mtile = blockIdx.y * 128, ntile = blockIdx.x * 128;
  int w = tid >> 6, l = tid & 63;
  int wr = w >> 1, wc = w & 1;
  int lr = l & 15, lg = l >> 4;

  f32x4 zero4 = {0.f, 0.f, 0.f, 0.f};
  f32x4 acc[4][4];
  #pragma unroll
  for (int i = 0; i < 4; ++i)
    #pragma unroll
    for (int j = 0; j < 4; ++j) acc[i][j] = zero4;

  for (int k0 = 0; k0 < K; k0 += 64) {
    __syncthreads();
    #pragma unroll
    for (int c = 0; c < 4; ++c) {
      int idx = tid + c * 256;
      int row = idx >> 3, kc = idx & 7;
      gl_lds16(&A[(size_t)(mtile + row) * K + k0 + kc * 8], &Al[idx * 8]);
      gl_lds16(&Bt[(size_t)(ntile + row) * K + k0 + kc * 8], &Bl[idx * 8]);
    }
    __syncthreads();
    __builtin_amdgcn_s_setprio(1);
    #pragma unroll
    for (int kk = 0; kk < 2; ++kk) {
      bf16x8 af[4], bfr[4];
      #pragma unroll
      for (int i = 0; i < 4; ++i)
        af[i] = *reinterpret_cast<const bf16x8*>(&Al[(wr * 64 + i * 16 + lr) * 64 + kk * 32 + lg * 8]);
      #pragma unroll
      for (int j = 0; j < 4; ++j)
        bfr[j] = *reinterpret_cast<const bf16x8*>(&Bl[(wc * 64 + j * 16 + lr) * 64 + kk * 32 + lg * 8]);
      #pragma unroll
      for (int i = 0; i < 4; ++i)
        #pragma unroll
        for (int j = 0; j < 4; ++j)
          acc[i][j] = __builtin_amdgcn_mfma_f32_16x16x32_bf16(af[i], bfr[j], acc[i][j], 0, 0, 0);
    }
    __builtin_amdgcn_s_setprio(0);
  }

  #pragma unroll
  for (int j = 0; j < 4; ++j) {
    int n = ntile + wc * 64 + j * 16 + lr;
    float bv = bias[n];
    #pragma unroll
    for (int i = 0; i < 4; ++i) {
      #pragma unroll
      for (int r = 0; r < 4; ++r) {
        int m = mtile + wr * 64 + i * 16 + lg * 4 + r;
        out[(size_t)m * 1024 + n] = acc[i][j][r] + bv;
      }
    }
  }
}

extern "C" void kernel_launch(void* const* d_in, const int* in_sizes, int n_in,
                              void* d_out, int out_size, void* d_ws, size_t ws_size,
                              hipStream_t stream) {
  const float* x     = (const float*)d_in[0];
  const float* Wqkv  = (const float*)d_in[1];
  const float* bqkv  = (const float*)d_in[2];
  const float* Wproj = (const float*)d_in[3];
  const float* bproj = (const float*)d_in[4];
  float* out = (float*)d_out;

  const size_t M4 = 4096ull * 1024ull;
  short* ws = (short*)d_ws;
  short* x_bf    = ws;
  short* wqkv_t  = ws + M4;
  short* wproj_t = ws + M4 + 3ull * 1024 * 1024;
  short* qb      = wproj_t + 1024ull * 1024;
  short* kb      = qb + M4;
  short* vtb     = kb + M4;     // [bh][64][2048] transposed V
  short* yb      = x_bf;        // alias: x_bf dead after gemm_qkv

  cast_x_kernel<<<4096, 256, 0, stream>>>(x, x_bf, (int)(M4 / 4));
  transpose_cast<<<dim3(48, 16), 256, 0, stream>>>(Wqkv, wqkv_t, 1024, 3072);
  transpose_cast<<<dim3(16, 16), 256, 0, stream>>>(Wproj, wproj_t, 1024, 1024);
  gemm_qkv<<<dim3(24, 32), 256, 0, stream>>>(x_bf, wqkv_t, bqkv, qb, kb, vtb);
  attn_kernel<<<1024, 256, 0, stream>>>(qb, kb, vtb, yb);
  gemm_proj<<<dim3(8, 32), 256, 0, stream>>>(yb, wproj_t, bproj, out);
}

// Round 13
// 163.311 us; speedup vs baseline: 1.0313x; 1.0313x over previous
//
#include <hip/hip_runtime.h>

// ---- types ----
typedef __bf16 bf16x8 __attribute__((ext_vector_type(8)));
typedef float  f32x4  __attribute__((ext_vector_type(4)));
typedef float  f32x16 __attribute__((ext_vector_type(16)));
typedef unsigned int uint32x4 __attribute__((ext_vector_type(4)));

__device__ __forceinline__ short f2bf(float f) {
  union { float f; unsigned u; } v; v.f = f;
  unsigned r = v.u + 0x7fffu + ((v.u >> 16) & 1u);
  return (short)(r >> 16);
}

// async global->LDS (16B per lane); LDS dest must be wave-uniform base + lane*16
__device__ __forceinline__ void gl_lds16(const short* g, short* l) {
  __builtin_amdgcn_global_load_lds((const __attribute__((address_space(1))) void*)g,
                                   (__attribute__((address_space(3))) void*)l, 16, 0, 0);
}

// ---- cast x fp32 -> bf16 (vectorized) ----
__global__ __launch_bounds__(256) void cast_x_kernel(const float* __restrict__ in,
                                                     short* __restrict__ out, int n4) {
  int i = blockIdx.x * 256 + threadIdx.x;
  if (i >= n4) return;
  float4 f = reinterpret_cast<const float4*>(in)[i];
  short4 o;
  o.x = f2bf(f.x); o.y = f2bf(f.y); o.z = f2bf(f.z); o.w = f2bf(f.w);
  reinterpret_cast<short4*>(out)[i] = o;
}

// ---- transpose + cast: in[R][Cc] fp32 -> out[Cc][R] bf16 ----
__global__ __launch_bounds__(256) void transpose_cast(const float* __restrict__ in,
                                                      short* __restrict__ out, int R, int Cc) {
  __shared__ short tile[64][65];
  int bx = blockIdx.x * 64;
  int by = blockIdx.y * 64;
  int tx = threadIdx.x & 63, ty = threadIdx.x >> 6;
  #pragma unroll
  for (int i = ty; i < 64; i += 4)
    tile[i][tx] = f2bf(in[(size_t)(by + i) * Cc + bx + tx]);
  __syncthreads();
  #pragma unroll
  for (int i = ty; i < 64; i += 4)
    out[(size_t)(bx + i) * R + by + tx] = tile[tx][i];
}

// ---- GEMM1: qkv = x_bf[4096][1024] * Wqkv_t[3072][1024]^T + bqkv
//      q,k -> [B2][H16][T2048][D64] bf16 (q scaled 0.125*log2e); v -> [BH][D64][T2048]
__global__ __launch_bounds__(256) void gemm_qkv(const short* __restrict__ A,
                                                const short* __restrict__ Bt,
                                                const float* __restrict__ bias,
                                                short* __restrict__ qo,
                                                short* __restrict__ ko,
                                                short* __restrict__ vt) {
  const int K = 1024;
  __shared__ short Al[8192];   // linear [128][64]
  __shared__ short Bl[8192];
  int tid = threadIdx.x;
  int mtile = blockIdx.y * 128, ntile = blockIdx.x * 128;
  int w = tid >> 6, l = tid & 63;
  int wr = w >> 1, wc = w & 1;
  int lr = l & 15, lg = l >> 4;

  f32x4 zero4 = {0.f, 0.f, 0.f, 0.f};
  f32x4 acc[4][4];
  #pragma unroll
  for (int i = 0; i < 4; ++i)
    #pragma unroll
    for (int j = 0; j < 4; ++j) acc[i][j] = zero4;

  for (int k0 = 0; k0 < K; k0 += 64) {
    __syncthreads();
    #pragma unroll
    for (int c = 0; c < 4; ++c) {
      int idx = tid + c * 256;
      int row = idx >> 3, kc = idx & 7;
      gl_lds16(&A[(size_t)(mtile + row) * K + k0 + kc * 8], &Al[idx * 8]);
      gl_lds16(&Bt[(size_t)(ntile + row) * K + k0 + kc * 8], &Bl[idx * 8]);
    }
    __syncthreads();
    __builtin_amdgcn_s_setprio(1);
    #pragma unroll
    for (int kk = 0; kk < 2; ++kk) {
      bf16x8 af[4], bfr[4];
      #pragma unroll
      for (int i = 0; i < 4; ++i)
        af[i] = *reinterpret_cast<const bf16x8*>(&Al[(wr * 64 + i * 16 + lr) * 64 + kk * 32 + lg * 8]);
      #pragma unroll
      for (int j = 0; j < 4; ++j)
        bfr[j] = *reinterpret_cast<const bf16x8*>(&Bl[(wc * 64 + j * 16 + lr) * 64 + kk * 32 + lg * 8]);
      #pragma unroll
      for (int i = 0; i < 4; ++i)
        #pragma unroll
        for (int j = 0; j < 4; ++j)
          acc[i][j] = __builtin_amdgcn_mfma_f32_16x16x32_bf16(af[i], bfr[j], acc[i][j], 0, 0, 0);
    }
    __builtin_amdgcn_s_setprio(0);
  }

  #pragma unroll
  for (int j = 0; j < 4; ++j) {
    int n = ntile + wc * 64 + j * 16 + lr;   // 0..3071 (sec uniform per block)
    float bv = bias[n];
    int sec = n >> 10;
    int ch = n & 1023;
    int h = ch >> 6, d = ch & 63;
    if (sec == 2) {
      #pragma unroll
      for (int i = 0; i < 4; ++i) {
        int t0g = mtile + wr * 64 + i * 16 + lg * 4;
        int bb = t0g >> 11, t = t0g & 2047;
        short4 pk;
        pk.x = f2bf(acc[i][j][0] + bv);
        pk.y = f2bf(acc[i][j][1] + bv);
        pk.z = f2bf(acc[i][j][2] + bv);
        pk.w = f2bf(acc[i][j][3] + bv);
        *reinterpret_cast<short4*>(&vt[((size_t)(bb * 16 + h) * 64 + d) * 2048 + t]) = pk;
      }
    } else {
      short* dst = (sec == 0) ? qo : ko;
      // q scaled by (1/sqrt(64)) * log2(e) so attention works in exp2 domain
      float sc = (sec == 0) ? 0.18033688f : 1.0f;
      #pragma unroll
      for (int i = 0; i < 4; ++i) {
        #pragma unroll
        for (int r = 0; r < 4; ++r) {
          int m = mtile + wr * 64 + i * 16 + lg * 4 + r;
          int bb = m >> 11, t = m & 2047;
          dst[(size_t)((bb * 16 + h) * 2048 + t) * 64 + d] = f2bf((acc[i][j][r] + bv) * sc);
        }
      }
    }
  }
}

// ---- flash attention v13: v6 (best, 72us) with HALVED merge LDS (two-pass y0/y1
//      merge) -> 13.3 KB/block -> occupancy LDS-cap 6 -> grid-cap 8 blocks/CU ----
template<int DIAG>
__device__ __forceinline__ void attn_step(const short* __restrict__ kp,
                                          const short* __restrict__ vp,
                                          const bf16x8* qf,
                                          f32x16& y0, f32x16& y1,
                                          float& m, float& li,
                                          int lq, int hl) {
  f32x16 s;
  #pragma unroll
  for (int r = 0; r < 16; ++r) s[r] = 0.f;
  __builtin_amdgcn_s_setprio(1);
  #pragma unroll
  for (int ks = 0; ks < 4; ++ks) {
    bf16x8 kf = *reinterpret_cast<const bf16x8*>(kp + ks * 16);
    s = __builtin_amdgcn_mfma_f32_32x32x16_bf16(kf, qf[ks], s, 0, 0, 0);
  }
  __builtin_amdgcn_s_setprio(0);
  if (DIAG) {
    #pragma unroll
    for (int r = 0; r < 16; ++r) {
      int kvl = (r & 3) + 8 * (r >> 2) + 4 * hl;
      if (kvl > lq) s[r] = -1e30f;
    }
  }
  float a0 = fmaxf(fmaxf(s[0], s[1]), fmaxf(s[2], s[3]));
  float a1 = fmaxf(fmaxf(s[4], s[5]), fmaxf(s[6], s[7]));
  float a2 = fmaxf(fmaxf(s[8], s[9]), fmaxf(s[10], s[11]));
  float a3 = fmaxf(fmaxf(s[12], s[13]), fmaxf(s[14], s[15]));
  float pm = fmaxf(fmaxf(a0, a1), fmaxf(a2, a3));
  pm = fmaxf(pm, __shfl_xor(pm, 32));
  if (!__all(pm - m <= 8.0f)) {
    float mn = fmaxf(m, pm);
    float sc = __builtin_amdgcn_exp2f(m - mn);
    m = mn;
    li *= sc;
    #pragma unroll
    for (int r = 0; r < 16; ++r) { y0[r] *= sc; y1[r] *= sc; }
  }
  unsigned u[8];
  float rs = 0.f;
  #pragma unroll
  for (int rq = 0; rq < 4; ++rq) {
    float p0 = __builtin_amdgcn_exp2f(s[4 * rq + 0] - m);
    float p1 = __builtin_amdgcn_exp2f(s[4 * rq + 1] - m);
    float p2 = __builtin_amdgcn_exp2f(s[4 * rq + 2] - m);
    float p3 = __builtin_amdgcn_exp2f(s[4 * rq + 3] - m);
    rs += (p0 + p1) + (p2 + p3);
    asm("v_cvt_pk_bf16_f32 %0, %1, %2" : "=v"(u[rq * 2 + 0]) : "v"(p0), "v"(p1));
    asm("v_cvt_pk_bf16_f32 %0, %1, %2" : "=v"(u[rq * 2 + 1]) : "v"(p2), "v"(p3));
  }
  rs += __shfl_xor(rs, 32);
  li += rs;
  asm volatile("v_permlane32_swap_b32 %0, %1" : "+v"(u[0]), "+v"(u[2]));
  asm volatile("v_permlane32_swap_b32 %0, %1" : "+v"(u[1]), "+v"(u[3]));
  asm volatile("v_permlane32_swap_b32 %0, %1" : "+v"(u[4]), "+v"(u[6]));
  asm volatile("v_permlane32_swap_b32 %0, %1" : "+v"(u[5]), "+v"(u[7]));
  uint32x4 w0 = {u[0], u[1], u[2], u[3]};
  uint32x4 w1 = {u[4], u[5], u[6], u[7]};
  bf16x8 pa0 = __builtin_bit_cast(bf16x8, w0);
  bf16x8 pa1 = __builtin_bit_cast(bf16x8, w1);
  __builtin_amdgcn_s_setprio(1);
  {
    bf16x8 vf00 = *reinterpret_cast<const bf16x8*>(vp);
    bf16x8 vf01 = *reinterpret_cast<const bf16x8*>(vp + 16);
    bf16x8 vf10 = *reinterpret_cast<const bf16x8*>(vp + 32 * 2048);
    bf16x8 vf11 = *reinterpret_cast<const bf16x8*>(vp + 32 * 2048 + 16);
    y0 = __builtin_amdgcn_mfma_f32_32x32x16_bf16(vf00, pa0, y0, 0, 0, 0);
    y0 = __builtin_amdgcn_mfma_f32_32x32x16_bf16(vf01, pa1, y0, 0, 0, 0);
    y1 = __builtin_amdgcn_mfma_f32_32x32x16_bf16(vf10, pa0, y1, 0, 0, 0);
    y1 = __builtin_amdgcn_mfma_f32_32x32x16_bf16(vf11, pa1, y1, 0, 0, 0);
  }
  __builtin_amdgcn_s_setprio(0);
}

__global__ __launch_bounds__(256, 4) void attn_kernel(const short* __restrict__ q,
                                                      const short* __restrict__ k,
                                                      const short* __restrict__ vt,
                                                      short* __restrict__ y) {
  __shared__ float partL[3][4][64][4];   // 12 KB, reused for y0 then y1 pass
  __shared__ float stm[4][32], stl[4][32];
  const int bid = blockIdx.x;
  const int t = 63 - (bid >> 5);           // longest-first
  const int b5 = bid & 31;
  const int bh = (b5 & 7) * 4 + (b5 >> 3); // group each bh's blocks on one XCD
  const int tid = threadIdx.x;
  const int w = tid >> 6;                  // wave: kv-split index 0..3
  const int l = tid & 63;
  const int lq = l & 31, hl = l >> 5;
  const short* qb = q + (size_t)bh * 131072;
  const short* kb = k + (size_t)bh * 131072;
  const short* vb = vt + (size_t)bh * 131072;   // [64][2048]

  // Q B-frags (k=64 -> 4 frags), shared q-tile for all 4 waves
  bf16x8 qf[4];
  {
    const short* qp = &qb[(size_t)(32 * t + lq) * 64 + hl * 8];
    #pragma unroll
    for (int ks = 0; ks < 4; ++ks)
      qf[ks] = *reinterpret_cast<const bf16x8*>(qp + ks * 16);
  }

  f32x16 y0, y1;
  #pragma unroll
  for (int r = 0; r < 16; ++r) { y0[r] = 0.f; y1[r] = 0.f; }
  float m = -1e30f, li = 0.f;

  // wave w handles kv tiles {w, w+4, ...} < t, plus diag tile t if t&3==w
  const short* kp = kb + (size_t)w * 2048 + (size_t)lq * 64 + hl * 8;
  const short* vp = vb + (size_t)lq * 2048 + w * 32 + hl * 8;
  for (int it = w; it < t; it += 4) {
    attn_step<0>(kp, vp, qf, y0, y1, m, li, lq, hl);
    kp += 4 * 2048;
    vp += 4 * 32;
  }
  if ((t & 3) == w) {
    const short* kpd = kb + (size_t)t * 2048 + (size_t)lq * 64 + hl * 8;
    const short* vpd = vb + (size_t)lq * 2048 + t * 32 + hl * 8;
    attn_step<1>(kpd, vpd, qf, y0, y1, m, li, lq, hl);
  }

  // ---- merge the 4 wave-partials (two passes over a half-size buffer) ----
  if (hl == 0) { stm[w][lq] = m; stl[w][lq] = li; }
  __syncthreads();
  float m0 = stm[0][lq], m1 = stm[1][lq], m2 = stm[2][lq], m3 = stm[3][lq];
  float M = fmaxf(fmaxf(m0, m1), fmaxf(m2, m3));
  float L = stl[0][lq] * __builtin_amdgcn_exp2f(m0 - M) +
            stl[1][lq] * __builtin_amdgcn_exp2f(m1 - M) +
            stl[2][lq] * __builtin_amdgcn_exp2f(m2 - M) +
            stl[3][lq] * __builtin_amdgcn_exp2f(m3 - M);
  float sc = __builtin_amdgcn_exp2f(m - M);
  #pragma unroll
  for (int r = 0; r < 16; ++r) { y0[r] *= sc; y1[r] *= sc; }

  // pass 0: merge y0
  if (w > 0) {
    #pragma unroll
    for (int c = 0; c < 4; ++c) {
      f32x4 v0 = {y0[4 * c + 0], y0[4 * c + 1], y0[4 * c + 2], y0[4 * c + 3]};
      *reinterpret_cast<f32x4*>(&partL[w - 1][c][l][0]) = v0;
    }
  }
  __syncthreads();
  if (w == 0) {
    #pragma unroll
    for (int o = 0; o < 3; ++o)
      #pragma unroll
      for (int c = 0; c < 4; ++c) {
        f32x4 v0 = *reinterpret_cast<const f32x4*>(&partL[o][c][l][0]);
        #pragma unroll
        for (int r = 0; r < 4; ++r) y0[4 * c + r] += v0[r];
      }
  }
  __syncthreads();
  // pass 1: merge y1 (buffer reused)
  if (w > 0) {
    #pragma unroll
    for (int c = 0; c < 4; ++c) {
      f32x4 v1 = {y1[4 * c + 0], y1[4 * c + 1], y1[4 * c + 2], y1[4 * c + 3]};
      *reinterpret_cast<f32x4*>(&partL[w - 1][c][l][0]) = v1;
    }
  }
  __syncthreads();
  if (w == 0) {
    #pragma unroll
    for (int o = 0; o < 3; ++o)
      #pragma unroll
      for (int c = 0; c < 4; ++c) {
        f32x4 v1 = *reinterpret_cast<const f32x4*>(&partL[o][c][l][0]);
        #pragma unroll
        for (int r = 0; r < 4; ++r) y1[4 * c + r] += v1[r];
      }
    float inv = 1.0f / L;
    int b_ = bh >> 4, h_ = bh & 15;
    short* yrow = &y[(size_t)(b_ * 2048 + 32 * t + lq) * 1024 + h_ * 64];
    #pragma unroll
    for (int dt = 0; dt < 2; ++dt) {
      const f32x16& yy = dt ? y1 : y0;
      #pragma unroll
      for (int rq = 0; rq < 4; ++rq) {
        int d0 = dt * 32 + 8 * rq + 4 * hl;
        uint2 pk;
        pk.x = (unsigned)(unsigned short)f2bf(yy[4 * rq + 0] * inv) |
               ((unsigned)(unsigned short)f2bf(yy[4 * rq + 1] * inv) << 16);
        pk.y = (unsigned)(unsigned short)f2bf(yy[4 * rq + 2] * inv) |
               ((unsigned)(unsigned short)f2bf(yy[4 * rq + 3] * inv) << 16);
        *reinterpret_cast<uint2*>(yrow + d0) = pk;
      }
    }
  }
}

// ---- GEMM3: out fp32 = y_bf[4096][1024] * Wproj_t[1024][1024]^T + bproj ----
__global__ __launch_bounds__(256) void gemm_proj(const short* __restrict__ A,
                                                 const short* __restrict__ Bt,
                                                 const float* __restrict__ bias,
                                                 float* __restrict__ out) {
  const int K = 1024;
  __shared__ short Al[8192];
  __shared__ short Bl[8192];
  int tid = threadIdx.x;
  int mtile = blockIdx.y * 128, ntile = blockIdx.x * 128;
  int w = tid >> 6, l = tid & 63;
  int wr = w >> 1, wc = w & 1;
  int lr = l & 15, lg = l >> 4;

  f32x4 zero4 = {0.f, 0.f, 0.f, 0.f};
  f32x4 acc[4][4];
  #pragma unroll
  for (int i = 0; i < 4; ++i)
    #pragma unroll
    for (int j = 0; j < 4; ++j) acc[i][j] = zero4;

  for (int k0 = 0; k0 < K; k0 += 64) {
    __syncthreads();
    #pragma unroll
    for (int c = 0; c < 4; ++c) {
      int idx = tid + c * 256;
      int row = idx >> 3, kc = idx & 7;
      gl_lds16(&A[(size_t)(mtile + row) * K + k0 + kc * 8], &Al[idx * 8]);
      gl_lds16(&Bt[(size_t)(ntile + row) * K + k0 + kc * 8], &Bl[idx * 8]);
    }
    __syncthreads();
    __builtin_amdgcn_s_setprio(1);
    #pragma unroll
    for (int kk = 0; kk < 2; ++kk) {
      bf16x8 af[4], bfr[4];
      #pragma unroll
      for (int i = 0; i < 4; ++i)
        af[i] = *reinterpret_cast<const bf16x8*>(&Al[(wr * 64 + i * 16 + lr) * 64 + kk * 32 + lg * 8]);
      #pragma unroll
      for (int j = 0; j < 4; ++j)
        bfr[j] = *reinterpret_cast<const bf16x8*>(&Bl[(wc * 64 + j * 16 + lr) * 64 + kk * 32 + lg * 8]);
      #pragma unroll
      for (int i = 0; i < 4; ++i)
        #pragma unroll
        for (int j = 0; j < 4; ++j)
          acc[i][j] = __builtin_amdgcn_mfma_f32_16x16x32_bf16(af[i], bfr[j], acc[i][j], 0, 0, 0);
    }
    __builtin_amdgcn_s_setprio(0);
  }

  #pragma unroll
  for (int j = 0; j < 4; ++j) {
    int n = ntile + wc * 64 + j * 16 + lr;
    float bv = bias[n];
    #pragma unroll
    for (int i = 0; i < 4; ++i) {
      #pragma unroll
      for (int r = 0; r < 4; ++r) {
        int m = mtile + wr * 64 + i * 16 + lg * 4 + r;
        out[(size_t)m * 1024 + n] = acc[i][j][r] + bv;
      }
    }
  }
}

extern "C" void kernel_launch(void* const* d_in, const int* in_sizes, int n_in,
                              void* d_out, int out_size, void* d_ws, size_t ws_size,
                              hipStream_t stream) {
  const float* x     = (const float*)d_in[0];
  const float* Wqkv  = (const float*)d_in[1];
  const float* bqkv  = (const float*)d_in[2];
  const float* Wproj = (const float*)d_in[3];
  const float* bproj = (const float*)d_in[4];
  float* out = (float*)d_out;

  const size_t M4 = 4096ull * 1024ull;
  short* ws = (short*)d_ws;
  short* x_bf    = ws;
  short* wqkv_t  = ws + M4;
  short* wproj_t = ws + M4 + 3ull * 1024 * 1024;
  short* qb      = wproj_t + 1024ull * 1024;
  short* kb      = qb + M4;
  short* vtb     = kb + M4;     // [bh][64][2048] transposed V
  short* yb      = x_bf;        // alias: x_bf dead after gemm_qkv

  cast_x_kernel<<<4096, 256, 0, stream>>>(x, x_bf, (int)(M4 / 4));
  transpose_cast<<<dim3(48, 16), 256, 0, stream>>>(Wqkv, wqkv_t, 1024, 3072);
  transpose_cast<<<dim3(16, 16), 256, 0, stream>>>(Wproj, wproj_t, 1024, 1024);
  gemm_qkv<<<dim3(24, 32), 256, 0, stream>>>(x_bf, wqkv_t, bqkv, qb, kb, vtb);
  attn_kernel<<<2048, 256, 0, stream>>>(qb, kb, vtb, yb);
  gemm_proj<<<dim3(8, 32), 256, 0, stream>>>(yb, wproj_t, bproj, out);
}

// Round 14
// 135.895 us; speedup vs baseline: 1.2393x; 1.2017x over previous
//
#include <hip/hip_runtime.h>

// ---- types ----
typedef __bf16 bf16x8 __attribute__((ext_vector_type(8)));
typedef float  f32x4  __attribute__((ext_vector_type(4)));
typedef float  f32x16 __attribute__((ext_vector_type(16)));
typedef unsigned int uint32x4 __attribute__((ext_vector_type(4)));

__device__ __forceinline__ short f2bf(float f) {
  union { float f; unsigned u; } v; v.f = f;
  unsigned r = v.u + 0x7fffu + ((v.u >> 16) & 1u);
  return (short)(r >> 16);
}

// async global->LDS (16B per lane); LDS dest must be wave-uniform base + lane*16
__device__ __forceinline__ void gl_lds16(const short* g, short* l) {
  __builtin_amdgcn_global_load_lds((const __attribute__((address_space(1))) void*)g,
                                   (__attribute__((address_space(3))) void*)l, 16, 0, 0);
}

// ---- cast x fp32 -> bf16 (vectorized) ----
__global__ __launch_bounds__(256) void cast_x_kernel(const float* __restrict__ in,
                                                     short* __restrict__ out, int n4) {
  int i = blockIdx.x * 256 + threadIdx.x;
  if (i >= n4) return;
  float4 f = reinterpret_cast<const float4*>(in)[i];
  short4 o;
  o.x = f2bf(f.x); o.y = f2bf(f.y); o.z = f2bf(f.z); o.w = f2bf(f.w);
  reinterpret_cast<short4*>(out)[i] = o;
}

// ---- transpose + cast: in[R][Cc] fp32 -> out[Cc][R] bf16 ----
__global__ __launch_bounds__(256) void transpose_cast(const float* __restrict__ in,
                                                      short* __restrict__ out, int R, int Cc) {
  __shared__ short tile[64][65];
  int bx = blockIdx.x * 64;
  int by = blockIdx.y * 64;
  int tx = threadIdx.x & 63, ty = threadIdx.x >> 6;
  #pragma unroll
  for (int i = ty; i < 64; i += 4)
    tile[i][tx] = f2bf(in[(size_t)(by + i) * Cc + bx + tx]);
  __syncthreads();
  #pragma unroll
  for (int i = ty; i < 64; i += 4)
    out[(size_t)(bx + i) * R + by + tx] = tile[tx][i];
}

// ==== swizzled fragment layouts (per bh, 64 tiles x 2048 shorts) ====
// Q/K: element (t,d) -> (t>>5)*2048 + ((((d>>3)&1)<<5)+(t&31))*32 + ((d>>4)<<3) + (d&7)
//   lane l of tile reads its 4 MFMA frags at l*32 + ks*8  (64B/lane, coalesced)
// V^T: element (d,t) -> (t>>5)*2048 + ((((t>>3)&1)<<5)+(d&31))*32
//                       + ((((t>>4)&1)+((d>>5)<<1))<<3) + (t&7)
//   lane l reads its 4 frags (c=0..3) at l*32 + c*8

// ---- GEMM1: qkv = x_bf[4096][1024] * Wqkv_t[3072][1024]^T + bqkv
//      q,k -> fragment-swizzled [BH][131072] (q scaled 0.125*log2e); v -> swizzled V^T
__global__ __launch_bounds__(256) void gemm_qkv(const short* __restrict__ A,
                                                const short* __restrict__ Bt,
                                                const float* __restrict__ bias,
                                                short* __restrict__ qo,
                                                short* __restrict__ ko,
                                                short* __restrict__ vt) {
  const int K = 1024;
  __shared__ short Al[8192];   // linear [128][64]
  __shared__ short Bl[8192];
  int tid = threadIdx.x;
  int mtile = blockIdx.y * 128, ntile = blockIdx.x * 128;
  int w = tid >> 6, l = tid & 63;
  int wr = w >> 1, wc = w & 1;
  int lr = l & 15, lg = l >> 4;

  f32x4 zero4 = {0.f, 0.f, 0.f, 0.f};
  f32x4 acc[4][4];
  #pragma unroll
  for (int i = 0; i < 4; ++i)
    #pragma unroll
    for (int j = 0; j < 4; ++j) acc[i][j] = zero4;

  for (int k0 = 0; k0 < K; k0 += 64) {
    __syncthreads();
    #pragma unroll
    for (int c = 0; c < 4; ++c) {
      int idx = tid + c * 256;
      int row = idx >> 3, kc = idx & 7;
      gl_lds16(&A[(size_t)(mtile + row) * K + k0 + kc * 8], &Al[idx * 8]);
      gl_lds16(&Bt[(size_t)(ntile + row) * K + k0 + kc * 8], &Bl[idx * 8]);
    }
    __syncthreads();
    __builtin_amdgcn_s_setprio(1);
    #pragma unroll
    for (int kk = 0; kk < 2; ++kk) {
      bf16x8 af[4], bfr[4];
      #pragma unroll
      for (int i = 0; i < 4; ++i)
        af[i] = *reinterpret_cast<const bf16x8*>(&Al[(wr * 64 + i * 16 + lr) * 64 + kk * 32 + lg * 8]);
      #pragma unroll
      for (int j = 0; j < 4; ++j)
        bfr[j] = *reinterpret_cast<const bf16x8*>(&Bl[(wc * 64 + j * 16 + lr) * 64 + kk * 32 + lg * 8]);
      #pragma unroll
      for (int i = 0; i < 4; ++i)
        #pragma unroll
        for (int j = 0; j < 4; ++j)
          acc[i][j] = __builtin_amdgcn_mfma_f32_16x16x32_bf16(af[i], bfr[j], acc[i][j], 0, 0, 0);
    }
    __builtin_amdgcn_s_setprio(0);
  }

  #pragma unroll
  for (int j = 0; j < 4; ++j) {
    int n = ntile + wc * 64 + j * 16 + lr;   // 0..3071 (sec uniform per block)
    float bv = bias[n];
    int sec = n >> 10;
    int ch = n & 1023;
    int h = ch >> 6, d = ch & 63;
    if (sec == 2) {
      // V^T fragment-swizzled; 4 consecutive t share (hl,c) -> short4 store
      #pragma unroll
      for (int i = 0; i < 4; ++i) {
        int t0g = mtile + wr * 64 + i * 16 + lg * 4;
        int bb = t0g >> 11, t = t0g & 2047;
        size_t off = (size_t)(bb * 16 + h) * 131072 +
                     (size_t)(t >> 5) * 2048 +
                     (size_t)((((t >> 3) & 1) << 5) + (d & 31)) * 32 +
                     ((((t >> 4) & 1) + ((d >> 5) << 1)) << 3) + (t & 7);
        short4 pk;
        pk.x = f2bf(acc[i][j][0] + bv);
        pk.y = f2bf(acc[i][j][1] + bv);
        pk.z = f2bf(acc[i][j][2] + bv);
        pk.w = f2bf(acc[i][j][3] + bv);
        *reinterpret_cast<short4*>(&vt[off]) = pk;
      }
    } else {
      short* dst = (sec == 0) ? qo : ko;
      // q scaled by (1/sqrt(64)) * log2(e) so attention works in exp2 domain
      float sc = (sec == 0) ? 0.18033688f : 1.0f;
      size_t dpart = (size_t)(((d >> 3) & 1) << 10) + ((d >> 4) << 3) + (d & 7);
      #pragma unroll
      for (int i = 0; i < 4; ++i) {
        #pragma unroll
        for (int r = 0; r < 4; ++r) {
          int m = mtile + wr * 64 + i * 16 + lg * 4 + r;
          int bb = m >> 11, t = m & 2047;
          size_t off = (size_t)(bb * 16 + h) * 131072 +
                       (size_t)(t >> 5) * 2048 + (size_t)(t & 31) * 32 + dpart;
          dst[off] = f2bf((acc[i][j][r] + bv) * sc);
        }
      }
    }
  }
}

// ---- flash attention v14: v13 + fragment-swizzled Q/K/V -> every global load
//      is lane-contiguous 64B (8 lines/instr instead of 32-64). ----
template<int DIAG>
__device__ __forceinline__ void attn_step(const short* __restrict__ kp,
                                          const short* __restrict__ vp,
                                          const bf16x8* qf,
                                          f32x16& y0, f32x16& y1,
                                          float& m, float& li,
                                          int lq, int hl) {
  f32x16 s;
  #pragma unroll
  for (int r = 0; r < 16; ++r) s[r] = 0.f;
  __builtin_amdgcn_s_setprio(1);
  #pragma unroll
  for (int ks = 0; ks < 4; ++ks) {
    bf16x8 kf = *reinterpret_cast<const bf16x8*>(kp + ks * 8);
    s = __builtin_amdgcn_mfma_f32_32x32x16_bf16(kf, qf[ks], s, 0, 0, 0);
  }
  __builtin_amdgcn_s_setprio(0);
  if (DIAG) {
    #pragma unroll
    for (int r = 0; r < 16; ++r) {
      int kvl = (r & 3) + 8 * (r >> 2) + 4 * hl;
      if (kvl > lq) s[r] = -1e30f;
    }
  }
  float a0 = fmaxf(fmaxf(s[0], s[1]), fmaxf(s[2], s[3]));
  float a1 = fmaxf(fmaxf(s[4], s[5]), fmaxf(s[6], s[7]));
  float a2 = fmaxf(fmaxf(s[8], s[9]), fmaxf(s[10], s[11]));
  float a3 = fmaxf(fmaxf(s[12], s[13]), fmaxf(s[14], s[15]));
  float pm = fmaxf(fmaxf(a0, a1), fmaxf(a2, a3));
  pm = fmaxf(pm, __shfl_xor(pm, 32));
  if (!__all(pm - m <= 8.0f)) {
    float mn = fmaxf(m, pm);
    float sc = __builtin_amdgcn_exp2f(m - mn);
    m = mn;
    li *= sc;
    #pragma unroll
    for (int r = 0; r < 16; ++r) { y0[r] *= sc; y1[r] *= sc; }
  }
  unsigned u[8];
  float rs = 0.f;
  #pragma unroll
  for (int rq = 0; rq < 4; ++rq) {
    float p0 = __builtin_amdgcn_exp2f(s[4 * rq + 0] - m);
    float p1 = __builtin_amdgcn_exp2f(s[4 * rq + 1] - m);
    float p2 = __builtin_amdgcn_exp2f(s[4 * rq + 2] - m);
    float p3 = __builtin_amdgcn_exp2f(s[4 * rq + 3] - m);
    rs += (p0 + p1) + (p2 + p3);
    asm("v_cvt_pk_bf16_f32 %0, %1, %2" : "=v"(u[rq * 2 + 0]) : "v"(p0), "v"(p1));
    asm("v_cvt_pk_bf16_f32 %0, %1, %2" : "=v"(u[rq * 2 + 1]) : "v"(p2), "v"(p3));
  }
  rs += __shfl_xor(rs, 32);
  li += rs;
  asm volatile("v_permlane32_swap_b32 %0, %1" : "+v"(u[0]), "+v"(u[2]));
  asm volatile("v_permlane32_swap_b32 %0, %1" : "+v"(u[1]), "+v"(u[3]));
  asm volatile("v_permlane32_swap_b32 %0, %1" : "+v"(u[4]), "+v"(u[6]));
  asm volatile("v_permlane32_swap_b32 %0, %1" : "+v"(u[5]), "+v"(u[7]));
  uint32x4 w0 = {u[0], u[1], u[2], u[3]};
  uint32x4 w1 = {u[4], u[5], u[6], u[7]};
  bf16x8 pa0 = __builtin_bit_cast(bf16x8, w0);
  bf16x8 pa1 = __builtin_bit_cast(bf16x8, w1);
  __builtin_amdgcn_s_setprio(1);
  {
    bf16x8 vf00 = *reinterpret_cast<const bf16x8*>(vp);        // c=0: d=lq,   kv lo
    bf16x8 vf01 = *reinterpret_cast<const bf16x8*>(vp + 8);    // c=1: d=lq,   kv hi
    bf16x8 vf10 = *reinterpret_cast<const bf16x8*>(vp + 16);   // c=2: d=lq+32,kv lo
    bf16x8 vf11 = *reinterpret_cast<const bf16x8*>(vp + 24);   // c=3: d=lq+32,kv hi
    y0 = __builtin_amdgcn_mfma_f32_32x32x16_bf16(vf00, pa0, y0, 0, 0, 0);
    y0 = __builtin_amdgcn_mfma_f32_32x32x16_bf16(vf01, pa1, y0, 0, 0, 0);
    y1 = __builtin_amdgcn_mfma_f32_32x32x16_bf16(vf10, pa0, y1, 0, 0, 0);
    y1 = __builtin_amdgcn_mfma_f32_32x32x16_bf16(vf11, pa1, y1, 0, 0, 0);
  }
  __builtin_amdgcn_s_setprio(0);
}

__global__ __launch_bounds__(256, 4) void attn_kernel(const short* __restrict__ q,
                                                      const short* __restrict__ k,
                                                      const short* __restrict__ vt,
                                                      short* __restrict__ y) {
  __shared__ float partL[3][4][64][4];   // 12 KB, reused for y0 then y1 pass
  __shared__ float stm[4][32], stl[4][32];
  const int bid = blockIdx.x;
  const int t = 63 - (bid >> 5);           // longest-first
  const int b5 = bid & 31;
  const int bh = (b5 & 7) * 4 + (b5 >> 3); // group each bh's blocks on one XCD
  const int tid = threadIdx.x;
  const int w = tid >> 6;                  // wave: kv-split index 0..3
  const int l = tid & 63;
  const int lq = l & 31, hl = l >> 5;
  const short* qb = q + (size_t)bh * 131072;
  const short* kb = k + (size_t)bh * 131072;
  const short* vb = vt + (size_t)bh * 131072;

  // Q fragments: swizzled -> one coalesced 64B read per lane
  bf16x8 qf[4];
  {
    const short* qp = qb + (size_t)t * 2048 + l * 32;
    #pragma unroll
    for (int ks = 0; ks < 4; ++ks)
      qf[ks] = *reinterpret_cast<const bf16x8*>(qp + ks * 8);
  }

  f32x16 y0, y1;
  #pragma unroll
  for (int r = 0; r < 16; ++r) { y0[r] = 0.f; y1[r] = 0.f; }
  float m = -1e30f, li = 0.f;

  // wave w handles kv tiles {w, w+4, ...} < t, plus diag tile t if t&3==w
  const short* kp = kb + (size_t)w * 2048 + l * 32;
  const short* vp = vb + (size_t)w * 2048 + l * 32;
  for (int it = w; it < t; it += 4) {
    attn_step<0>(kp, vp, qf, y0, y1, m, li, lq, hl);
    kp += 4 * 2048;
    vp += 4 * 2048;
  }
  if ((t & 3) == w) {
    const short* kpd = kb + (size_t)t * 2048 + l * 32;
    const short* vpd = vb + (size_t)t * 2048 + l * 32;
    attn_step<1>(kpd, vpd, qf, y0, y1, m, li, lq, hl);
  }

  // ---- merge the 4 wave-partials (two passes over a half-size buffer) ----
  if (hl == 0) { stm[w][lq] = m; stl[w][lq] = li; }
  __syncthreads();
  float m0 = stm[0][lq], m1 = stm[1][lq], m2 = stm[2][lq], m3 = stm[3][lq];
  float M = fmaxf(fmaxf(m0, m1), fmaxf(m2, m3));
  float L = stl[0][lq] * __builtin_amdgcn_exp2f(m0 - M) +
            stl[1][lq] * __builtin_amdgcn_exp2f(m1 - M) +
            stl[2][lq] * __builtin_amdgcn_exp2f(m2 - M) +
            stl[3][lq] * __builtin_amdgcn_exp2f(m3 - M);
  float sc = __builtin_amdgcn_exp2f(m - M);
  #pragma unroll
  for (int r = 0; r < 16; ++r) { y0[r] *= sc; y1[r] *= sc; }

  // pass 0: merge y0
  if (w > 0) {
    #pragma unroll
    for (int c = 0; c < 4; ++c) {
      f32x4 v0 = {y0[4 * c + 0], y0[4 * c + 1], y0[4 * c + 2], y0[4 * c + 3]};
      *reinterpret_cast<f32x4*>(&partL[w - 1][c][l][0]) = v0;
    }
  }
  __syncthreads();
  if (w == 0) {
    #pragma unroll
    for (int o = 0; o < 3; ++o)
      #pragma unroll
      for (int c = 0; c < 4; ++c) {
        f32x4 v0 = *reinterpret_cast<const f32x4*>(&partL[o][c][l][0]);
        #pragma unroll
        for (int r = 0; r < 4; ++r) y0[4 * c + r] += v0[r];
      }
  }
  __syncthreads();
  // pass 1: merge y1 (buffer reused)
  if (w > 0) {
    #pragma unroll
    for (int c = 0; c < 4; ++c) {
      f32x4 v1 = {y1[4 * c + 0], y1[4 * c + 1], y1[4 * c + 2], y1[4 * c + 3]};
      *reinterpret_cast<f32x4*>(&partL[w - 1][c][l][0]) = v1;
    }
  }
  __syncthreads();
  if (w == 0) {
    #pragma unroll
    for (int o = 0; o < 3; ++o)
      #pragma unroll
      for (int c = 0; c < 4; ++c) {
        f32x4 v1 = *reinterpret_cast<const f32x4*>(&partL[o][c][l][0]);
        #pragma unroll
        for (int r = 0; r < 4; ++r) y1[4 * c + r] += v1[r];
      }
    float inv = 1.0f / L;
    int b_ = bh >> 4, h_ = bh & 15;
    short* yrow = &y[(size_t)(b_ * 2048 + 32 * t + lq) * 1024 + h_ * 64];
    #pragma unroll
    for (int dt = 0; dt < 2; ++dt) {
      const f32x16& yy = dt ? y1 : y0;
      #pragma unroll
      for (int rq = 0; rq < 4; ++rq) {
        int d0 = dt * 32 + 8 * rq + 4 * hl;
        uint2 pk;
        pk.x = (unsigned)(unsigned short)f2bf(yy[4 * rq + 0] * inv) |
               ((unsigned)(unsigned short)f2bf(yy[4 * rq + 1] * inv) << 16);
        pk.y = (unsigned)(unsigned short)f2bf(yy[4 * rq + 2] * inv) |
               ((unsigned)(unsigned short)f2bf(yy[4 * rq + 3] * inv) << 16);
        *reinterpret_cast<uint2*>(yrow + d0) = pk;
      }
    }
  }
}

// ---- GEMM3: out fp32 = y_bf[4096][1024] * Wproj_t[1024][1024]^T + bproj ----
__global__ __launch_bounds__(256) void gemm_proj(const short* __restrict__ A,
                                                 const short* __restrict__ Bt,
                                                 const float* __restrict__ bias,
                                                 float* __restrict__ out) {
  const int K = 1024;
  __shared__ short Al[8192];
  __shared__ short Bl[8192];
  int tid = threadIdx.x;
  int mtile = blockIdx.y * 128, ntile = blockIdx.x * 128;
  int w = tid >> 6, l = tid & 63;
  int wr = w >> 1, wc = w & 1;
  int lr = l & 15, lg = l >> 4;

  f32x4 zero4 = {0.f, 0.f, 0.f, 0.f};
  f32x4 acc[4][4];
  #pragma unroll
  for (int i = 0; i < 4; ++i)
    #pragma unroll
    for (int j = 0; j < 4; ++j) acc[i][j] = zero4;

  for (int k0 = 0; k0 < K; k0 += 64) {
    __syncthreads();
    #pragma unroll
    for (int c = 0; c < 4; ++c) {
      int idx = tid + c * 256;
      int row = idx >> 3, kc = idx & 7;
      gl_lds16(&A[(size_t)(mtile + row) * K + k0 + kc * 8], &Al[idx * 8]);
      gl_lds16(&Bt[(size_t)(ntile + row) * K + k0 + kc * 8], &Bl[idx * 8]);
    }
    __syncthreads();
    __builtin_amdgcn_s_setprio(1);
    #pragma unroll
    for (int kk = 0; kk < 2; ++kk) {
      bf16x8 af[4], bfr[4];
      #pragma unroll
      for (int i = 0; i < 4; ++i)
        af[i] = *reinterpret_cast<const bf16x8*>(&Al[(wr * 64 + i * 16 + lr) * 64 + kk * 32 + lg * 8]);
      #pragma unroll
      for (int j = 0; j < 4; ++j)
        bfr[j] = *reinterpret_cast<const bf16x8*>(&Bl[(wc * 64 + j * 16 + lr) * 64 + kk * 32 + lg * 8]);
      #pragma unroll
      for (int i = 0; i < 4; ++i)
        #pragma unroll
        for (int j = 0; j < 4; ++j)
          acc[i][j] = __builtin_amdgcn_mfma_f32_16x16x32_bf16(af[i], bfr[j], acc[i][j], 0, 0, 0);
    }
    __builtin_amdgcn_s_setprio(0);
  }

  #pragma unroll
  for (int j = 0; j < 4; ++j) {
    int n = ntile + wc * 64 + j * 16 + lr;
    float bv = bias[n];
    #pragma unroll
    for (int i = 0; i < 4; ++i) {
      #pragma unroll
      for (int r = 0; r < 4; ++r) {
        int m = mtile + wr * 64 + i * 16 + lg * 4 + r;
        out[(size_t)m * 1024 + n] = acc[i][j][r] + bv;
      }
    }
  }
}

extern "C" void kernel_launch(void* const* d_in, const int* in_sizes, int n_in,
                              void* d_out, int out_size, void* d_ws, size_t ws_size,
                              hipStream_t stream) {
  const float* x     = (const float*)d_in[0];
  const float* Wqkv  = (const float*)d_in[1];
  const float* bqkv  = (const float*)d_in[2];
  const float* Wproj = (const float*)d_in[3];
  const float* bproj = (const float*)d_in[4];
  float* out = (float*)d_out;

  const size_t M4 = 4096ull * 1024ull;
  short* ws = (short*)d_ws;
  short* x_bf    = ws;
  short* wqkv_t  = ws + M4;
  short* wproj_t = ws + M4 + 3ull * 1024 * 1024;
  short* qb      = wproj_t + 1024ull * 1024;
  short* kb      = qb + M4;
  short* vtb     = kb + M4;     // fragment-swizzled V^T
  short* yb      = x_bf;        // alias: x_bf dead after gemm_qkv

  cast_x_kernel<<<4096, 256, 0, stream>>>(x, x_bf, (int)(M4 / 4));
  transpose_cast<<<dim3(48, 16), 256, 0, stream>>>(Wqkv, wqkv_t, 1024, 3072);
  transpose_cast<<<dim3(16, 16), 256, 0, stream>>>(Wproj, wproj_t, 1024, 1024);
  gemm_qkv<<<dim3(24, 32), 256, 0, stream>>>(x_bf, wqkv_t, bqkv, qb, kb, vtb);
  attn_kernel<<<2048, 256, 0, stream>>>(qb, kb, vtb, yb);
  gemm_proj<<<dim3(8, 32), 256, 0, stream>>>(yb, wproj_t, bproj, out);
}

// Round 15
// 134.418 us; speedup vs baseline: 1.2530x; 1.0110x over previous
//
#include <hip/hip_runtime.h>

// ---- types ----
typedef __bf16 bf16x8 __attribute__((ext_vector_type(8)));
typedef float  f32x4  __attribute__((ext_vector_type(4)));
typedef float  f32x16 __attribute__((ext_vector_type(16)));
typedef unsigned int uint32x4 __attribute__((ext_vector_type(4)));

__device__ __forceinline__ short f2bf(float f) {
  union { float f; unsigned u; } v; v.f = f;
  unsigned r = v.u + 0x7fffu + ((v.u >> 16) & 1u);
  return (short)(r >> 16);
}

// async global->LDS (16B per lane); LDS dest must be wave-uniform base + lane*16
__device__ __forceinline__ void gl_lds16(const short* g, short* l) {
  __builtin_amdgcn_global_load_lds((const __attribute__((address_space(1))) void*)g,
                                   (__attribute__((address_space(3))) void*)l, 16, 0, 0);
}

// ---- cast x fp32 -> bf16 (vectorized) ----
__global__ __launch_bounds__(256) void cast_x_kernel(const float* __restrict__ in,
                                                     short* __restrict__ out, int n4) {
  int i = blockIdx.x * 256 + threadIdx.x;
  if (i >= n4) return;
  float4 f = reinterpret_cast<const float4*>(in)[i];
  short4 o;
  o.x = f2bf(f.x); o.y = f2bf(f.y); o.z = f2bf(f.z); o.w = f2bf(f.w);
  reinterpret_cast<short4*>(out)[i] = o;
}

// ---- transpose + cast: in[R][Cc] fp32 -> out[Cc][R] bf16 ----
__global__ __launch_bounds__(256) void transpose_cast(const float* __restrict__ in,
                                                      short* __restrict__ out, int R, int Cc) {
  __shared__ short tile[64][65];
  int bx = blockIdx.x * 64;
  int by = blockIdx.y * 64;
  int tx = threadIdx.x & 63, ty = threadIdx.x >> 6;
  #pragma unroll
  for (int i = ty; i < 64; i += 4)
    tile[i][tx] = f2bf(in[(size_t)(by + i) * Cc + bx + tx]);
  __syncthreads();
  #pragma unroll
  for (int i = ty; i < 64; i += 4)
    out[(size_t)(bx + i) * R + by + tx] = tile[tx][i];
}

// ==== swizzled fragment layouts (per bh, 64 tiles x 2048 shorts) ====
// Q/K: element (t,d) -> (t>>5)*2048 + ((((d>>3)&1)<<5)+(t&31))*32 + ((d>>4)<<3) + (d&7)
//   -> within-chunk pos = (t&31)*32 + (((d>>3)&1)<<10) + ((d>>4)<<3) + (d&7)
// V^T: element (d,t) -> (t>>5)*2048 + ((((t>>3)&1)<<5)+(d&31))*32
//                       + ((((t>>4)&1)+((d>>5)<<1))<<3) + (t&7)

// ---- GEMM1: qkv = x_bf[4096][1024] * Wqkv_t[3072][1024]^T + bqkv
//      q,k -> fragment-swizzled (q scaled 0.125*log2e); v -> swizzled V^T
//      epilogue v2: stage through LDS (Al/Bl reused) -> fully coalesced chunk stores
__global__ __launch_bounds__(256) void gemm_qkv(const short* __restrict__ A,
                                                const short* __restrict__ Bt,
                                                const float* __restrict__ bias,
                                                short* __restrict__ qo,
                                                short* __restrict__ ko,
                                                short* __restrict__ vt) {
  const int K = 1024;
  __shared__ short smem[16384];   // Al[0..8191] | Bl[8192..16383]; reused as 32KB out-stage
  short* Al = smem;
  short* Bl = smem + 8192;
  int tid = threadIdx.x;
  int mtile = blockIdx.y * 128, ntile = blockIdx.x * 128;
  int w = tid >> 6, l = tid & 63;
  int wr = w >> 1, wc = w & 1;
  int lr = l & 15, lg = l >> 4;

  f32x4 zero4 = {0.f, 0.f, 0.f, 0.f};
  f32x4 acc[4][4];
  #pragma unroll
  for (int i = 0; i < 4; ++i)
    #pragma unroll
    for (int j = 0; j < 4; ++j) acc[i][j] = zero4;

  for (int k0 = 0; k0 < K; k0 += 64) {
    __syncthreads();
    #pragma unroll
    for (int c = 0; c < 4; ++c) {
      int idx = tid + c * 256;
      int row = idx >> 3, kc = idx & 7;
      gl_lds16(&A[(size_t)(mtile + row) * K + k0 + kc * 8], &Al[idx * 8]);
      gl_lds16(&Bt[(size_t)(ntile + row) * K + k0 + kc * 8], &Bl[idx * 8]);
    }
    __syncthreads();
    __builtin_amdgcn_s_setprio(1);
    #pragma unroll
    for (int kk = 0; kk < 2; ++kk) {
      bf16x8 af[4], bfr[4];
      #pragma unroll
      for (int i = 0; i < 4; ++i)
        af[i] = *reinterpret_cast<const bf16x8*>(&Al[(wr * 64 + i * 16 + lr) * 64 + kk * 32 + lg * 8]);
      #pragma unroll
      for (int j = 0; j < 4; ++j)
        bfr[j] = *reinterpret_cast<const bf16x8*>(&Bl[(wc * 64 + j * 16 + lr) * 64 + kk * 32 + lg * 8]);
      #pragma unroll
      for (int i = 0; i < 4; ++i)
        #pragma unroll
        for (int j = 0; j < 4; ++j)
          acc[i][j] = __builtin_amdgcn_mfma_f32_16x16x32_bf16(af[i], bfr[j], acc[i][j], 0, 0, 0);
    }
    __builtin_amdgcn_s_setprio(0);
  }

  // ---- epilogue: bias+scale+cvt -> LDS (final swizzled layout) -> coalesced stores
  __syncthreads();   // all waves done reading Al/Bl
  const int sec = ntile >> 10;   // 0=q 1=k 2=v (uniform per block)
  if (sec == 2) {
    #pragma unroll
    for (int j = 0; j < 4; ++j) {
      int nl = wc * 64 + j * 16 + lr;        // n - ntile, [0,128)
      int d  = nl & 63;                      // within-head channel
      float bv = bias[ntile + nl];
      #pragma unroll
      for (int i = 0; i < 4; ++i) {
        int lt0 = wr * 64 + i * 16 + lg * 4; // local t, r=0 (r spans t&7 consecutively)
        int c2 = (nl >> 6) * 4 + (lt0 >> 5);
        int pos = ((((lt0 >> 3) & 1) << 5) + (d & 31)) * 32 +
                  ((((lt0 >> 4) & 1) + ((d >> 5) << 1)) << 3) + (lt0 & 7);
        short4 pk;
        pk.x = f2bf(acc[i][j][0] + bv);
        pk.y = f2bf(acc[i][j][1] + bv);
        pk.z = f2bf(acc[i][j][2] + bv);
        pk.w = f2bf(acc[i][j][3] + bv);
        *reinterpret_cast<short4*>(&smem[c2 * 2048 + pos]) = pk;
      }
    }
  } else {
    // q scaled by (1/sqrt(64)) * log2(e) so attention works in exp2 domain
    const float sc = (sec == 0) ? 0.18033688f : 1.0f;
    #pragma unroll
    for (int j = 0; j < 4; ++j) {
      int nl = wc * 64 + j * 16 + lr;
      int d  = nl & 63;
      float bv = bias[ntile + nl];
      int dpart = (((d >> 3) & 1) << 10) + ((d >> 4) << 3) + (d & 7);
      #pragma unroll
      for (int i = 0; i < 4; ++i) {
        #pragma unroll
        for (int r = 0; r < 4; ++r) {
          int lt = wr * 64 + i * 16 + lg * 4 + r;
          int c2 = (nl >> 6) * 4 + (lt >> 5);
          smem[c2 * 2048 + (lt & 31) * 32 + dpart] = f2bf((acc[i][j][r] + bv) * sc);
        }
      }
    }
  }
  __syncthreads();
  short* dst = (sec == 0) ? qo : ((sec == 1) ? ko : vt);
  int bb  = mtile >> 11;
  int h0  = (ntile & 1023) >> 6;
  int gt0 = (mtile & 2047) >> 5;
  #pragma unroll
  for (int c2 = 0; c2 < 8; ++c2) {
    size_t base = (size_t)(bb * 16 + h0 + (c2 >> 2)) * 131072 +
                  (size_t)(gt0 + (c2 & 3)) * 2048;
    *reinterpret_cast<uint4*>(&dst[base + tid * 8]) =
        *reinterpret_cast<const uint4*>(&smem[c2 * 2048 + tid * 8]);
  }
}

// ---- flash attention v14: fragment-swizzled Q/K/V -> every global load is
//      lane-contiguous 64B (8 lines/instr). kv-split + two-pass merge. ----
template<int DIAG>
__device__ __forceinline__ void attn_step(const short* __restrict__ kp,
                                          const short* __restrict__ vp,
                                          const bf16x8* qf,
                                          f32x16& y0, f32x16& y1,
                                          float& m, float& li,
                                          int lq, int hl) {
  f32x16 s;
  #pragma unroll
  for (int r = 0; r < 16; ++r) s[r] = 0.f;
  __builtin_amdgcn_s_setprio(1);
  #pragma unroll
  for (int ks = 0; ks < 4; ++ks) {
    bf16x8 kf = *reinterpret_cast<const bf16x8*>(kp + ks * 8);
    s = __builtin_amdgcn_mfma_f32_32x32x16_bf16(kf, qf[ks], s, 0, 0, 0);
  }
  __builtin_amdgcn_s_setprio(0);
  if (DIAG) {
    #pragma unroll
    for (int r = 0; r < 16; ++r) {
      int kvl = (r & 3) + 8 * (r >> 2) + 4 * hl;
      if (kvl > lq) s[r] = -1e30f;
    }
  }
  float a0 = fmaxf(fmaxf(s[0], s[1]), fmaxf(s[2], s[3]));
  float a1 = fmaxf(fmaxf(s[4], s[5]), fmaxf(s[6], s[7]));
  float a2 = fmaxf(fmaxf(s[8], s[9]), fmaxf(s[10], s[11]));
  float a3 = fmaxf(fmaxf(s[12], s[13]), fmaxf(s[14], s[15]));
  float pm = fmaxf(fmaxf(a0, a1), fmaxf(a2, a3));
  pm = fmaxf(pm, __shfl_xor(pm, 32));
  if (!__all(pm - m <= 8.0f)) {
    float mn = fmaxf(m, pm);
    float sc = __builtin_amdgcn_exp2f(m - mn);
    m = mn;
    li *= sc;
    #pragma unroll
    for (int r = 0; r < 16; ++r) { y0[r] *= sc; y1[r] *= sc; }
  }
  unsigned u[8];
  float rs = 0.f;
  #pragma unroll
  for (int rq = 0; rq < 4; ++rq) {
    float p0 = __builtin_amdgcn_exp2f(s[4 * rq + 0] - m);
    float p1 = __builtin_amdgcn_exp2f(s[4 * rq + 1] - m);
    float p2 = __builtin_amdgcn_exp2f(s[4 * rq + 2] - m);
    float p3 = __builtin_amdgcn_exp2f(s[4 * rq + 3] - m);
    rs += (p0 + p1) + (p2 + p3);
    asm("v_cvt_pk_bf16_f32 %0, %1, %2" : "=v"(u[rq * 2 + 0]) : "v"(p0), "v"(p1));
    asm("v_cvt_pk_bf16_f32 %0, %1, %2" : "=v"(u[rq * 2 + 1]) : "v"(p2), "v"(p3));
  }
  rs += __shfl_xor(rs, 32);
  li += rs;
  asm volatile("v_permlane32_swap_b32 %0, %1" : "+v"(u[0]), "+v"(u[2]));
  asm volatile("v_permlane32_swap_b32 %0, %1" : "+v"(u[1]), "+v"(u[3]));
  asm volatile("v_permlane32_swap_b32 %0, %1" : "+v"(u[4]), "+v"(u[6]));
  asm volatile("v_permlane32_swap_b32 %0, %1" : "+v"(u[5]), "+v"(u[7]));
  uint32x4 w0 = {u[0], u[1], u[2], u[3]};
  uint32x4 w1 = {u[4], u[5], u[6], u[7]};
  bf16x8 pa0 = __builtin_bit_cast(bf16x8, w0);
  bf16x8 pa1 = __builtin_bit_cast(bf16x8, w1);
  __builtin_amdgcn_s_setprio(1);
  {
    bf16x8 vf00 = *reinterpret_cast<const bf16x8*>(vp);
    bf16x8 vf01 = *reinterpret_cast<const bf16x8*>(vp + 8);
    bf16x8 vf10 = *reinterpret_cast<const bf16x8*>(vp + 16);
    bf16x8 vf11 = *reinterpret_cast<const bf16x8*>(vp + 24);
    y0 = __builtin_amdgcn_mfma_f32_32x32x16_bf16(vf00, pa0, y0, 0, 0, 0);
    y0 = __builtin_amdgcn_mfma_f32_32x32x16_bf16(vf01, pa1, y0, 0, 0, 0);
    y1 = __builtin_amdgcn_mfma_f32_32x32x16_bf16(vf10, pa0, y1, 0, 0, 0);
    y1 = __builtin_amdgcn_mfma_f32_32x32x16_bf16(vf11, pa1, y1, 0, 0, 0);
  }
  __builtin_amdgcn_s_setprio(0);
}

__global__ __launch_bounds__(256, 4) void attn_kernel(const short* __restrict__ q,
                                                      const short* __restrict__ k,
                                                      const short* __restrict__ vt,
                                                      short* __restrict__ y) {
  __shared__ float partL[3][4][64][4];   // 12 KB, reused for y0 then y1 pass
  __shared__ float stm[4][32], stl[4][32];
  const int bid = blockIdx.x;
  const int t = 63 - (bid >> 5);           // longest-first
  const int b5 = bid & 31;
  const int bh = (b5 & 7) * 4 + (b5 >> 3); // group each bh's blocks on one XCD
  const int tid = threadIdx.x;
  const int w = tid >> 6;                  // wave: kv-split index 0..3
  const int l = tid & 63;
  const int lq = l & 31, hl = l >> 5;
  const short* qb = q + (size_t)bh * 131072;
  const short* kb = k + (size_t)bh * 131072;
  const short* vb = vt + (size_t)bh * 131072;

  // Q fragments: swizzled -> one coalesced 64B read per lane
  bf16x8 qf[4];
  {
    const short* qp = qb + (size_t)t * 2048 + l * 32;
    #pragma unroll
    for (int ks = 0; ks < 4; ++ks)
      qf[ks] = *reinterpret_cast<const bf16x8*>(qp + ks * 8);
  }

  f32x16 y0, y1;
  #pragma unroll
  for (int r = 0; r < 16; ++r) { y0[r] = 0.f; y1[r] = 0.f; }
  float m = -1e30f, li = 0.f;

  // wave w handles kv tiles {w, w+4, ...} < t, plus diag tile t if t&3==w
  const short* kp = kb + (size_t)w * 2048 + l * 32;
  const short* vp = vb + (size_t)w * 2048 + l * 32;
  for (int it = w; it < t; it += 4) {
    attn_step<0>(kp, vp, qf, y0, y1, m, li, lq, hl);
    kp += 4 * 2048;
    vp += 4 * 2048;
  }
  if ((t & 3) == w) {
    const short* kpd = kb + (size_t)t * 2048 + l * 32;
    const short* vpd = vb + (size_t)t * 2048 + l * 32;
    attn_step<1>(kpd, vpd, qf, y0, y1, m, li, lq, hl);
  }

  // ---- merge the 4 wave-partials (two passes over a half-size buffer) ----
  if (hl == 0) { stm[w][lq] = m; stl[w][lq] = li; }
  __syncthreads();
  float m0 = stm[0][lq], m1 = stm[1][lq], m2 = stm[2][lq], m3 = stm[3][lq];
  float M = fmaxf(fmaxf(m0, m1), fmaxf(m2, m3));
  float L = stl[0][lq] * __builtin_amdgcn_exp2f(m0 - M) +
            stl[1][lq] * __builtin_amdgcn_exp2f(m1 - M) +
            stl[2][lq] * __builtin_amdgcn_exp2f(m2 - M) +
            stl[3][lq] * __builtin_amdgcn_exp2f(m3 - M);
  float sc = __builtin_amdgcn_exp2f(m - M);
  #pragma unroll
  for (int r = 0; r < 16; ++r) { y0[r] *= sc; y1[r] *= sc; }

  // pass 0: merge y0
  if (w > 0) {
    #pragma unroll
    for (int c = 0; c < 4; ++c) {
      f32x4 v0 = {y0[4 * c + 0], y0[4 * c + 1], y0[4 * c + 2], y0[4 * c + 3]};
      *reinterpret_cast<f32x4*>(&partL[w - 1][c][l][0]) = v0;
    }
  }
  __syncthreads();
  if (w == 0) {
    #pragma unroll
    for (int o = 0; o < 3; ++o)
      #pragma unroll
      for (int c = 0; c < 4; ++c) {
        f32x4 v0 = *reinterpret_cast<const f32x4*>(&partL[o][c][l][0]);
        #pragma unroll
        for (int r = 0; r < 4; ++r) y0[4 * c + r] += v0[r];
      }
  }
  __syncthreads();
  // pass 1: merge y1 (buffer reused)
  if (w > 0) {
    #pragma unroll
    for (int c = 0; c < 4; ++c) {
      f32x4 v1 = {y1[4 * c + 0], y1[4 * c + 1], y1[4 * c + 2], y1[4 * c + 3]};
      *reinterpret_cast<f32x4*>(&partL[w - 1][c][l][0]) = v1;
    }
  }
  __syncthreads();
  if (w == 0) {
    #pragma unroll
    for (int o = 0; o < 3; ++o)
      #pragma unroll
      for (int c = 0; c < 4; ++c) {
        f32x4 v1 = *reinterpret_cast<const f32x4*>(&partL[o][c][l][0]);
        #pragma unroll
        for (int r = 0; r < 4; ++r) y1[4 * c + r] += v1[r];
      }
    float inv = 1.0f / L;
    int b_ = bh >> 4, h_ = bh & 15;
    short* yrow = &y[(size_t)(b_ * 2048 + 32 * t + lq) * 1024 + h_ * 64];
    #pragma unroll
    for (int dt = 0; dt < 2; ++dt) {
      const f32x16& yy = dt ? y1 : y0;
      #pragma unroll
      for (int rq = 0; rq < 4; ++rq) {
        int d0 = dt * 32 + 8 * rq + 4 * hl;
        uint2 pk;
        pk.x = (unsigned)(unsigned short)f2bf(yy[4 * rq + 0] * inv) |
               ((unsigned)(unsigned short)f2bf(yy[4 * rq + 1] * inv) << 16);
        pk.y = (unsigned)(unsigned short)f2bf(yy[4 * rq + 2] * inv) |
               ((unsigned)(unsigned short)f2bf(yy[4 * rq + 3] * inv) << 16);
        *reinterpret_cast<uint2*>(yrow + d0) = pk;
      }
    }
  }
}

// ---- GEMM3: out fp32 = y_bf[4096][1024] * Wproj_t[1024][1024]^T + bproj ----
__global__ __launch_bounds__(256) void gemm_proj(const short* __restrict__ A,
                                                 const short* __restrict__ Bt,
                                                 const float* __restrict__ bias,
                                                 float* __restrict__ out) {
  const int K = 1024;
  __shared__ short Al[8192];
  __shared__ short Bl[8192];
  int tid = threadIdx.x;
  int mtile = blockIdx.y * 128, ntile = blockIdx.x * 128;
  int w = tid >> 6, l = tid & 63;
  int wr = w >> 1, wc = w & 1;
  int lr = l & 15, lg = l >> 4;

  f32x4 zero4 = {0.f, 0.f, 0.f, 0.f};
  f32x4 acc[4][4];
  #pragma unroll
  for (int i = 0; i < 4; ++i)
    #pragma unroll
    for (int j = 0; j < 4; ++j) acc[i][j] = zero4;

  for (int k0 = 0; k0 < K; k0 += 64) {
    __syncthreads();
    #pragma unroll
    for (int c = 0; c < 4; ++c) {
      int idx = tid + c * 256;
      int row = idx >> 3, kc = idx & 7;
      gl_lds16(&A[(size_t)(mtile + row) * K + k0 + kc * 8], &Al[idx * 8]);
      gl_lds16(&Bt[(size_t)(ntile + row) * K + k0 + kc * 8], &Bl[idx * 8]);
    }
    __syncthreads();
    __builtin_amdgcn_s_setprio(1);
    #pragma unroll
    for (int kk = 0; kk < 2; ++kk) {
      bf16x8 af[4], bfr[4];
      #pragma unroll
      for (int i = 0; i < 4; ++i)
        af[i] = *reinterpret_cast<const bf16x8*>(&Al[(wr * 64 + i * 16 + lr) * 64 + kk * 32 + lg * 8]);
      #pragma unroll
      for (int j = 0; j < 4; ++j)
        bfr[j] = *reinterpret_cast<const bf16x8*>(&Bl[(wc * 64 + j * 16 + lr) * 64 + kk * 32 + lg * 8]);
      #pragma unroll
      for (int i = 0; i < 4; ++i)
        #pragma unroll
        for (int j = 0; j < 4; ++j)
          acc[i][j] = __builtin_amdgcn_mfma_f32_16x16x32_bf16(af[i], bfr[j], acc[i][j], 0, 0, 0);
    }
    __builtin_amdgcn_s_setprio(0);
  }

  #pragma unroll
  for (int j = 0; j < 4; ++j) {
    int n = ntile + wc * 64 + j * 16 + lr;
    float bv = bias[n];
    #pragma unroll
    for (int i = 0; i < 4; ++i) {
      #pragma unroll
      for (int r = 0; r < 4; ++r) {
        int m = mtile + wr * 64 + i * 16 + lg * 4 + r;
        out[(size_t)m * 1024 + n] = acc[i][j][r] + bv;
      }
    }
  }
}

extern "C" void kernel_launch(void* const* d_in, const int* in_sizes, int n_in,
                              void* d_out, int out_size, void* d_ws, size_t ws_size,
                              hipStream_t stream) {
  const float* x     = (const float*)d_in[0];
  const float* Wqkv  = (const float*)d_in[1];
  const float* bqkv  = (const float*)d_in[2];
  const float* Wproj = (const float*)d_in[3];
  const float* bproj = (const float*)d_in[4];
  float* out = (float*)d_out;

  const size_t M4 = 4096ull * 1024ull;
  short* ws = (short*)d_ws;
  short* x_bf    = ws;
  short* wqkv_t  = ws + M4;
  short* wproj_t = ws + M4 + 3ull * 1024 * 1024;
  short* qb      = wproj_t + 1024ull * 1024;
  short* kb      = qb + M4;
  short* vtb     = kb + M4;     // fragment-swizzled V^T
  short* yb      = x_bf;        // alias: x_bf dead after gemm_qkv

  cast_x_kernel<<<4096, 256, 0, stream>>>(x, x_bf, (int)(M4 / 4));
  transpose_cast<<<dim3(48, 16), 256, 0, stream>>>(Wqkv, wqkv_t, 1024, 3072);
  transpose_cast<<<dim3(16, 16), 256, 0, stream>>>(Wproj, wproj_t, 1024, 1024);
  gemm_qkv<<<dim3(24, 32), 256, 0, stream>>>(x_bf, wqkv_t, bqkv, qb, kb, vtb);
  attn_kernel<<<2048, 256, 0, stream>>>(qb, kb, vtb, yb);
  gemm_proj<<<dim3(8, 32), 256, 0, stream>>>(yb, wproj_t, bproj, out);
}

// Round 16
// 131.519 us; speedup vs baseline: 1.2806x; 1.0220x over previous
//
#include <hip/hip_runtime.h>

// ---- types ----
typedef __bf16 bf16x8 __attribute__((ext_vector_type(8)));
typedef float  f32x4  __attribute__((ext_vector_type(4)));
typedef float  f32x16 __attribute__((ext_vector_type(16)));
typedef unsigned int uint32x4 __attribute__((ext_vector_type(4)));

__device__ __forceinline__ short f2bf(float f) {
  union { float f; unsigned u; } v; v.f = f;
  unsigned r = v.u + 0x7fffu + ((v.u >> 16) & 1u);
  return (short)(r >> 16);
}

// async global->LDS (16B per lane); LDS dest must be wave-uniform base + lane*16
__device__ __forceinline__ void gl_lds16(const short* g, short* l) {
  __builtin_amdgcn_global_load_lds((const __attribute__((address_space(1))) void*)g,
                                   (__attribute__((address_space(3))) void*)l, 16, 0, 0);
}

// ---- cast x fp32 -> bf16 (vectorized) ----
__global__ __launch_bounds__(256) void cast_x_kernel(const float* __restrict__ in,
                                                     short* __restrict__ out, int n4) {
  int i = blockIdx.x * 256 + threadIdx.x;
  if (i >= n4) return;
  float4 f = reinterpret_cast<const float4*>(in)[i];
  short4 o;
  o.x = f2bf(f.x); o.y = f2bf(f.y); o.z = f2bf(f.z); o.w = f2bf(f.w);
  reinterpret_cast<short4*>(out)[i] = o;
}

// ---- transpose + cast: in[R][Cc] fp32 -> out[Cc][R] bf16 ----
__global__ __launch_bounds__(256) void transpose_cast(const float* __restrict__ in,
                                                      short* __restrict__ out, int R, int Cc) {
  __shared__ short tile[64][65];
  int bx = blockIdx.x * 64;
  int by = blockIdx.y * 64;
  int tx = threadIdx.x & 63, ty = threadIdx.x >> 6;
  #pragma unroll
  for (int i = ty; i < 64; i += 4)
    tile[i][tx] = f2bf(in[(size_t)(by + i) * Cc + bx + tx]);
  __syncthreads();
  #pragma unroll
  for (int i = ty; i < 64; i += 4)
    out[(size_t)(bx + i) * R + by + tx] = tile[tx][i];
}

// ==== swizzled fragment layouts (per bh, 64 tiles x 2048 shorts) ====
// Q/K: (t,d) -> (t>>5)*2048 + (((d>>3)&1)<<10) + (t&31)*32 + ((d>>4)<<3) + (d&7)
// V^T: (d,t) -> (t>>5)*2048 + (((t>>3)&1)<<10) + (d&31)*32
//               + ((((t>>4)&1)+((d>>5)<<1))<<3) + (t&7)

// ---- GEMM1 v3: BM=128 x BN=64 tiles (1536 blocks = 6/CU for TLP);
//      q,k fragment-swizzled (q scaled 0.125*log2e); v swizzled V^T;
//      LDS-staged coalesced epilogue (each block = one head x 128 tokens) ----
__global__ __launch_bounds__(256, 4) void gemm_qkv(const short* __restrict__ A,
                                                   const short* __restrict__ Bt,
                                                   const float* __restrict__ bias,
                                                   short* __restrict__ qo,
                                                   short* __restrict__ ko,
                                                   short* __restrict__ vt) {
  const int K = 1024;
  __shared__ short smem[12288];   // Al[0..8191] | Bl[8192..12287] (24 KB); reused 16KB out-stage
  short* Al = smem;
  short* Bl = smem + 8192;
  int tid = threadIdx.x;
  int ntile = blockIdx.x * 64, mtile = blockIdx.y * 128;
  int w = tid >> 6, l = tid & 63;
  int lr = l & 15, lg = l >> 4;

  f32x4 zero4 = {0.f, 0.f, 0.f, 0.f};
  f32x4 acc[2][4];
  #pragma unroll
  for (int i = 0; i < 2; ++i)
    #pragma unroll
    for (int j = 0; j < 4; ++j) acc[i][j] = zero4;

  for (int k0 = 0; k0 < K; k0 += 64) {
    __syncthreads();
    #pragma unroll
    for (int c = 0; c < 4; ++c) {
      int idx = tid + c * 256;
      int row = idx >> 3, kc = idx & 7;
      gl_lds16(&A[(size_t)(mtile + row) * K + k0 + kc * 8], &Al[idx * 8]);
    }
    #pragma unroll
    for (int c = 0; c < 2; ++c) {
      int idx = tid + c * 256;
      int row = idx >> 3, kc = idx & 7;
      gl_lds16(&Bt[(size_t)(ntile + row) * K + k0 + kc * 8], &Bl[idx * 8]);
    }
    __syncthreads();
    __builtin_amdgcn_s_setprio(1);
    #pragma unroll
    for (int kk = 0; kk < 2; ++kk) {
      bf16x8 af[2], bfr[4];
      #pragma unroll
      for (int i = 0; i < 2; ++i)
        af[i] = *reinterpret_cast<const bf16x8*>(&Al[(w * 32 + i * 16 + lr) * 64 + kk * 32 + lg * 8]);
      #pragma unroll
      for (int j = 0; j < 4; ++j)
        bfr[j] = *reinterpret_cast<const bf16x8*>(&Bl[(j * 16 + lr) * 64 + kk * 32 + lg * 8]);
      #pragma unroll
      for (int i = 0; i < 2; ++i)
        #pragma unroll
        for (int j = 0; j < 4; ++j)
          acc[i][j] = __builtin_amdgcn_mfma_f32_16x16x32_bf16(af[i], bfr[j], acc[i][j], 0, 0, 0);
    }
    __builtin_amdgcn_s_setprio(0);
  }

  // ---- epilogue: bias+scale+cvt -> LDS at final swizzled positions -> coalesced stores
  __syncthreads();
  const int sec = ntile >> 10;   // 0=q 1=k 2=v (uniform per block)
  if (sec == 2) {
    #pragma unroll
    for (int j = 0; j < 4; ++j) {
      int d = j * 16 + lr;                  // within-head channel (block = one head)
      float bv = bias[ntile + d];
      #pragma unroll
      for (int i = 0; i < 2; ++i) {
        int lt0 = w * 32 + i * 16 + lg * 4; // r spans lt&7 consecutively
        int pos = (((lt0 >> 3) & 1) << 10) + (d & 31) * 32 +
                  ((((lt0 >> 4) & 1) + ((d >> 5) << 1)) << 3) + (lt0 & 7);
        short4 pk;
        pk.x = f2bf(acc[i][j][0] + bv);
        pk.y = f2bf(acc[i][j][1] + bv);
        pk.z = f2bf(acc[i][j][2] + bv);
        pk.w = f2bf(acc[i][j][3] + bv);
        *reinterpret_cast<short4*>(&smem[(lt0 >> 5) * 2048 + pos]) = pk;
      }
    }
  } else {
    // q scaled by (1/sqrt(64)) * log2(e) so attention works in exp2 domain
    const float sc = (sec == 0) ? 0.18033688f : 1.0f;
    #pragma unroll
    for (int j = 0; j < 4; ++j) {
      int d = j * 16 + lr;
      float bv = bias[ntile + d];
      int dpart = (((d >> 3) & 1) << 10) + ((d >> 4) << 3) + (d & 7);
      #pragma unroll
      for (int i = 0; i < 2; ++i) {
        #pragma unroll
        for (int r = 0; r < 4; ++r) {
          int lt = w * 32 + i * 16 + lg * 4 + r;
          smem[(lt >> 5) * 2048 + (lt & 31) * 32 + dpart] = f2bf((acc[i][j][r] + bv) * sc);
        }
      }
    }
  }
  __syncthreads();
  short* dst = (sec == 0) ? qo : ((sec == 1) ? ko : vt);
  int bb  = mtile >> 11;
  int h0  = (ntile & 1023) >> 6;
  int gt0 = (mtile & 2047) >> 5;
  #pragma unroll
  for (int c2 = 0; c2 < 4; ++c2) {
    size_t base = (size_t)(bb * 16 + h0) * 131072 + (size_t)(gt0 + c2) * 2048;
    *reinterpret_cast<uint4*>(&dst[base + tid * 8]) =
        *reinterpret_cast<const uint4*>(&smem[c2 * 2048 + tid * 8]);
  }
}

// ---- flash attention v14: fragment-swizzled Q/K/V -> every global load is
//      lane-contiguous 64B (8 lines/instr). kv-split + two-pass merge. ----
template<int DIAG>
__device__ __forceinline__ void attn_step(const short* __restrict__ kp,
                                          const short* __restrict__ vp,
                                          const bf16x8* qf,
                                          f32x16& y0, f32x16& y1,
                                          float& m, float& li,
                                          int lq, int hl) {
  f32x16 s;
  #pragma unroll
  for (int r = 0; r < 16; ++r) s[r] = 0.f;
  __builtin_amdgcn_s_setprio(1);
  #pragma unroll
  for (int ks = 0; ks < 4; ++ks) {
    bf16x8 kf = *reinterpret_cast<const bf16x8*>(kp + ks * 8);
    s = __builtin_amdgcn_mfma_f32_32x32x16_bf16(kf, qf[ks], s, 0, 0, 0);
  }
  __builtin_amdgcn_s_setprio(0);
  if (DIAG) {
    #pragma unroll
    for (int r = 0; r < 16; ++r) {
      int kvl = (r & 3) + 8 * (r >> 2) + 4 * hl;
      if (kvl > lq) s[r] = -1e30f;
    }
  }
  float a0 = fmaxf(fmaxf(s[0], s[1]), fmaxf(s[2], s[3]));
  float a1 = fmaxf(fmaxf(s[4], s[5]), fmaxf(s[6], s[7]));
  float a2 = fmaxf(fmaxf(s[8], s[9]), fmaxf(s[10], s[11]));
  float a3 = fmaxf(fmaxf(s[12], s[13]), fmaxf(s[14], s[15]));
  float pm = fmaxf(fmaxf(a0, a1), fmaxf(a2, a3));
  pm = fmaxf(pm, __shfl_xor(pm, 32));
  if (!__all(pm - m <= 8.0f)) {
    float mn = fmaxf(m, pm);
    float sc = __builtin_amdgcn_exp2f(m - mn);
    m = mn;
    li *= sc;
    #pragma unroll
    for (int r = 0; r < 16; ++r) { y0[r] *= sc; y1[r] *= sc; }
  }
  unsigned u[8];
  float rs = 0.f;
  #pragma unroll
  for (int rq = 0; rq < 4; ++rq) {
    float p0 = __builtin_amdgcn_exp2f(s[4 * rq + 0] - m);
    float p1 = __builtin_amdgcn_exp2f(s[4 * rq + 1] - m);
    float p2 = __builtin_amdgcn_exp2f(s[4 * rq + 2] - m);
    float p3 = __builtin_amdgcn_exp2f(s[4 * rq + 3] - m);
    rs += (p0 + p1) + (p2 + p3);
    asm("v_cvt_pk_bf16_f32 %0, %1, %2" : "=v"(u[rq * 2 + 0]) : "v"(p0), "v"(p1));
    asm("v_cvt_pk_bf16_f32 %0, %1, %2" : "=v"(u[rq * 2 + 1]) : "v"(p2), "v"(p3));
  }
  rs += __shfl_xor(rs, 32);
  li += rs;
  asm volatile("v_permlane32_swap_b32 %0, %1" : "+v"(u[0]), "+v"(u[2]));
  asm volatile("v_permlane32_swap_b32 %0, %1" : "+v"(u[1]), "+v"(u[3]));
  asm volatile("v_permlane32_swap_b32 %0, %1" : "+v"(u[4]), "+v"(u[6]));
  asm volatile("v_permlane32_swap_b32 %0, %1" : "+v"(u[5]), "+v"(u[7]));
  uint32x4 w0 = {u[0], u[1], u[2], u[3]};
  uint32x4 w1 = {u[4], u[5], u[6], u[7]};
  bf16x8 pa0 = __builtin_bit_cast(bf16x8, w0);
  bf16x8 pa1 = __builtin_bit_cast(bf16x8, w1);
  __builtin_amdgcn_s_setprio(1);
  {
    bf16x8 vf00 = *reinterpret_cast<const bf16x8*>(vp);
    bf16x8 vf01 = *reinterpret_cast<const bf16x8*>(vp + 8);
    bf16x8 vf10 = *reinterpret_cast<const bf16x8*>(vp + 16);
    bf16x8 vf11 = *reinterpret_cast<const bf16x8*>(vp + 24);
    y0 = __builtin_amdgcn_mfma_f32_32x32x16_bf16(vf00, pa0, y0, 0, 0, 0);
    y0 = __builtin_amdgcn_mfma_f32_32x32x16_bf16(vf01, pa1, y0, 0, 0, 0);
    y1 = __builtin_amdgcn_mfma_f32_32x32x16_bf16(vf10, pa0, y1, 0, 0, 0);
    y1 = __builtin_amdgcn_mfma_f32_32x32x16_bf16(vf11, pa1, y1, 0, 0, 0);
  }
  __builtin_amdgcn_s_setprio(0);
}

__global__ __launch_bounds__(256, 4) void attn_kernel(const short* __restrict__ q,
                                                      const short* __restrict__ k,
                                                      const short* __restrict__ vt,
                                                      short* __restrict__ y) {
  __shared__ float partL[3][4][64][4];   // 12 KB, reused for y0 then y1 pass
  __shared__ float stm[4][32], stl[4][32];
  const int bid = blockIdx.x;
  const int t = 63 - (bid >> 5);           // longest-first
  const int b5 = bid & 31;
  const int bh = (b5 & 7) * 4 + (b5 >> 3); // group each bh's blocks on one XCD
  const int tid = threadIdx.x;
  const int w = tid >> 6;                  // wave: kv-split index 0..3
  const int l = tid & 63;
  const int lq = l & 31, hl = l >> 5;
  const short* qb = q + (size_t)bh * 131072;
  const short* kb = k + (size_t)bh * 131072;
  const short* vb = vt + (size_t)bh * 131072;

  // Q fragments: swizzled -> one coalesced 64B read per lane
  bf16x8 qf[4];
  {
    const short* qp = qb + (size_t)t * 2048 + l * 32;
    #pragma unroll
    for (int ks = 0; ks < 4; ++ks)
      qf[ks] = *reinterpret_cast<const bf16x8*>(qp + ks * 8);
  }

  f32x16 y0, y1;
  #pragma unroll
  for (int r = 0; r < 16; ++r) { y0[r] = 0.f; y1[r] = 0.f; }
  float m = -1e30f, li = 0.f;

  // wave w handles kv tiles {w, w+4, ...} < t, plus diag tile t if t&3==w
  const short* kp = kb + (size_t)w * 2048 + l * 32;
  const short* vp = vb + (size_t)w * 2048 + l * 32;
  for (int it = w; it < t; it += 4) {
    attn_step<0>(kp, vp, qf, y0, y1, m, li, lq, hl);
    kp += 4 * 2048;
    vp += 4 * 2048;
  }
  if ((t & 3) == w) {
    const short* kpd = kb + (size_t)t * 2048 + l * 32;
    const short* vpd = vb + (size_t)t * 2048 + l * 32;
    attn_step<1>(kpd, vpd, qf, y0, y1, m, li, lq, hl);
  }

  // ---- merge the 4 wave-partials (two passes over a half-size buffer) ----
  if (hl == 0) { stm[w][lq] = m; stl[w][lq] = li; }
  __syncthreads();
  float m0 = stm[0][lq], m1 = stm[1][lq], m2 = stm[2][lq], m3 = stm[3][lq];
  float M = fmaxf(fmaxf(m0, m1), fmaxf(m2, m3));
  float L = stl[0][lq] * __builtin_amdgcn_exp2f(m0 - M) +
            stl[1][lq] * __builtin_amdgcn_exp2f(m1 - M) +
            stl[2][lq] * __builtin_amdgcn_exp2f(m2 - M) +
            stl[3][lq] * __builtin_amdgcn_exp2f(m3 - M);
  float sc = __builtin_amdgcn_exp2f(m - M);
  #pragma unroll
  for (int r = 0; r < 16; ++r) { y0[r] *= sc; y1[r] *= sc; }

  // pass 0: merge y0
  if (w > 0) {
    #pragma unroll
    for (int c = 0; c < 4; ++c) {
      f32x4 v0 = {y0[4 * c + 0], y0[4 * c + 1], y0[4 * c + 2], y0[4 * c + 3]};
      *reinterpret_cast<f32x4*>(&partL[w - 1][c][l][0]) = v0;
    }
  }
  __syncthreads();
  if (w == 0) {
    #pragma unroll
    for (int o = 0; o < 3; ++o)
      #pragma unroll
      for (int c = 0; c < 4; ++c) {
        f32x4 v0 = *reinterpret_cast<const f32x4*>(&partL[o][c][l][0]);
        #pragma unroll
        for (int r = 0; r < 4; ++r) y0[4 * c + r] += v0[r];
      }
  }
  __syncthreads();
  // pass 1: merge y1 (buffer reused)
  if (w > 0) {
    #pragma unroll
    for (int c = 0; c < 4; ++c) {
      f32x4 v1 = {y1[4 * c + 0], y1[4 * c + 1], y1[4 * c + 2], y1[4 * c + 3]};
      *reinterpret_cast<f32x4*>(&partL[w - 1][c][l][0]) = v1;
    }
  }
  __syncthreads();
  if (w == 0) {
    #pragma unroll
    for (int o = 0; o < 3; ++o)
      #pragma unroll
      for (int c = 0; c < 4; ++c) {
        f32x4 v1 = *reinterpret_cast<const f32x4*>(&partL[o][c][l][0]);
        #pragma unroll
        for (int r = 0; r < 4; ++r) y1[4 * c + r] += v1[r];
      }
    float inv = 1.0f / L;
    int b_ = bh >> 4, h_ = bh & 15;
    short* yrow = &y[(size_t)(b_ * 2048 + 32 * t + lq) * 1024 + h_ * 64];
    #pragma unroll
    for (int dt = 0; dt < 2; ++dt) {
      const f32x16& yy = dt ? y1 : y0;
      #pragma unroll
      for (int rq = 0; rq < 4; ++rq) {
        int d0 = dt * 32 + 8 * rq + 4 * hl;
        uint2 pk;
        pk.x = (unsigned)(unsigned short)f2bf(yy[4 * rq + 0] * inv) |
               ((unsigned)(unsigned short)f2bf(yy[4 * rq + 1] * inv) << 16);
        pk.y = (unsigned)(unsigned short)f2bf(yy[4 * rq + 2] * inv) |
               ((unsigned)(unsigned short)f2bf(yy[4 * rq + 3] * inv) << 16);
        *reinterpret_cast<uint2*>(yrow + d0) = pk;
      }
    }
  }
}

// ---- GEMM3 v2: BM=128 x BN=64 (512 blocks = 2/CU);
//      out fp32 = y_bf[4096][1024] * Wproj_t[1024][1024]^T + bproj ----
__global__ __launch_bounds__(256, 4) void gemm_proj(const short* __restrict__ A,
                                                    const short* __restrict__ Bt,
                                                    const float* __restrict__ bias,
                                                    float* __restrict__ out) {
  const int K = 1024;
  __shared__ short Al[8192];
  __shared__ short Bl[4096];
  int tid = threadIdx.x;
  int ntile = blockIdx.x * 64, mtile = blockIdx.y * 128;
  int w = tid >> 6, l = tid & 63;
  int lr = l & 15, lg = l >> 4;

  f32x4 zero4 = {0.f, 0.f, 0.f, 0.f};
  f32x4 acc[2][4];
  #pragma unroll
  for (int i = 0; i < 2; ++i)
    #pragma unroll
    for (int j = 0; j < 4; ++j) acc[i][j] = zero4;

  for (int k0 = 0; k0 < K; k0 += 64) {
    __syncthreads();
    #pragma unroll
    for (int c = 0; c < 4; ++c) {
      int idx = tid + c * 256;
      int row = idx >> 3, kc = idx & 7;
      gl_lds16(&A[(size_t)(mtile + row) * K + k0 + kc * 8], &Al[idx * 8]);
    }
    #pragma unroll
    for (int c = 0; c < 2; ++c) {
      int idx = tid + c * 256;
      int row = idx >> 3, kc = idx & 7;
      gl_lds16(&Bt[(size_t)(ntile + row) * K + k0 + kc * 8], &Bl[idx * 8]);
    }
    __syncthreads();
    __builtin_amdgcn_s_setprio(1);
    #pragma unroll
    for (int kk = 0; kk < 2; ++kk) {
      bf16x8 af[2], bfr[4];
      #pragma unroll
      for (int i = 0; i < 2; ++i)
        af[i] = *reinterpret_cast<const bf16x8*>(&Al[(w * 32 + i * 16 + lr) * 64 + kk * 32 + lg * 8]);
      #pragma unroll
      for (int j = 0; j < 4; ++j)
        bfr[j] = *reinterpret_cast<const bf16x8*>(&Bl[(j * 16 + lr) * 64 + kk * 32 + lg * 8]);
      #pragma unroll
      for (int i = 0; i < 2; ++i)
        #pragma unroll
        for (int j = 0; j < 4; ++j)
          acc[i][j] = __builtin_amdgcn_mfma_f32_16x16x32_bf16(af[i], bfr[j], acc[i][j], 0, 0, 0);
    }
    __builtin_amdgcn_s_setprio(0);
  }

  #pragma unroll
  for (int j = 0; j < 4; ++j) {
    int n = ntile + j * 16 + lr;
    float bv = bias[n];
    #pragma unroll
    for (int i = 0; i < 2; ++i) {
      #pragma unroll
      for (int r = 0; r < 4; ++r) {
        int m = mtile + w * 32 + i * 16 + lg * 4 + r;
        out[(size_t)m * 1024 + n] = acc[i][j][r] + bv;
      }
    }
  }
}

extern "C" void kernel_launch(void* const* d_in, const int* in_sizes, int n_in,
                              void* d_out, int out_size, void* d_ws, size_t ws_size,
                              hipStream_t stream) {
  const float* x     = (const float*)d_in[0];
  const float* Wqkv  = (const float*)d_in[1];
  const float* bqkv  = (const float*)d_in[2];
  const float* Wproj = (const float*)d_in[3];
  const float* bproj = (const float*)d_in[4];
  float* out = (float*)d_out;

  const size_t M4 = 4096ull * 1024ull;
  short* ws = (short*)d_ws;
  short* x_bf    = ws;
  short* wqkv_t  = ws + M4;
  short* wproj_t = ws + M4 + 3ull * 1024 * 1024;
  short* qb      = wproj_t + 1024ull * 1024;
  short* kb      = qb + M4;
  short* vtb     = kb + M4;     // fragment-swizzled V^T
  short* yb      = x_bf;        // alias: x_bf dead after gemm_qkv

  cast_x_kernel<<<4096, 256, 0, stream>>>(x, x_bf, (int)(M4 / 4));
  transpose_cast<<<dim3(48, 16), 256, 0, stream>>>(Wqkv, wqkv_t, 1024, 3072);
  transpose_cast<<<dim3(16, 16), 256, 0, stream>>>(Wproj, wproj_t, 1024, 1024);
  gemm_qkv<<<dim3(48, 32), 256, 0, stream>>>(x_bf, wqkv_t, bqkv, qb, kb, vtb);
  attn_kernel<<<2048, 256, 0, stream>>>(qb, kb, vtb, yb);
  gemm_proj<<<dim3(16, 32), 256, 0, stream>>>(yb, wproj_t, bproj, out);
}

// Round 17
// 122.061 us; speedup vs baseline: 1.3798x; 1.0775x over previous
//
#include <hip/hip_runtime.h>

// ---- types ----
typedef __bf16 bf16x8 __attribute__((ext_vector_type(8)));
typedef float  f32x4  __attribute__((ext_vector_type(4)));
typedef float  f32x16 __attribute__((ext_vector_type(16)));
typedef unsigned int uint32x4 __attribute__((ext_vector_type(4)));

__device__ __forceinline__ short f2bf(float f) {
  union { float f; unsigned u; } v; v.f = f;
  unsigned r = v.u + 0x7fffu + ((v.u >> 16) & 1u);
  return (short)(r >> 16);
}

// async global->LDS (16B per lane); LDS dest must be wave-uniform base + lane*16
__device__ __forceinline__ void gl_lds16(const short* g, short* l) {
  __builtin_amdgcn_global_load_lds((const __attribute__((address_space(1))) void*)g,
                                   (__attribute__((address_space(3))) void*)l, 16, 0, 0);
}

// ---- cast x fp32 -> bf16 (vectorized) ----
__global__ __launch_bounds__(256) void cast_x_kernel(const float* __restrict__ in,
                                                     short* __restrict__ out, int n4) {
  int i = blockIdx.x * 256 + threadIdx.x;
  if (i >= n4) return;
  float4 f = reinterpret_cast<const float4*>(in)[i];
  short4 o;
  o.x = f2bf(f.x); o.y = f2bf(f.y); o.z = f2bf(f.z); o.w = f2bf(f.w);
  reinterpret_cast<short4*>(out)[i] = o;
}

// ---- transpose + cast: in[R][Cc] fp32 -> out[Cc][R] bf16 ----
__global__ __launch_bounds__(256) void transpose_cast(const float* __restrict__ in,
                                                      short* __restrict__ out, int R, int Cc) {
  __shared__ short tile[64][65];
  int bx = blockIdx.x * 64;
  int by = blockIdx.y * 64;
  int tx = threadIdx.x & 63, ty = threadIdx.x >> 6;
  #pragma unroll
  for (int i = ty; i < 64; i += 4)
    tile[i][tx] = f2bf(in[(size_t)(by + i) * Cc + bx + tx]);
  __syncthreads();
  #pragma unroll
  for (int i = ty; i < 64; i += 4)
    out[(size_t)(bx + i) * R + by + tx] = tile[tx][i];
}

// ==== swizzled fragment layouts (per bh, 64 tiles x 2048 shorts) ====
// Q/K: (t,d) -> (t>>5)*2048 + (((d>>3)&1)<<10) + (t&31)*32 + ((d>>4)<<3) + (d&7)
// V^T: (d,t) -> (t>>5)*2048 + (((t>>3)&1)<<10) + (d&31)*32
//               + ((((t>>4)&1)+((d>>5)<<1))<<3) + (t&7)

// ---- GEMM1 v4: BM=128 x BN=64, 2-PHASE double-buffered pipeline (T3-min):
//      STAGE(next) issued BEFORE compute(cur); ONE barrier per K-step so the
//      compiler's vmcnt(0)-drain lands after compute. LDS 2x24KB. ----
__global__ __launch_bounds__(256, 3) void gemm_qkv(const short* __restrict__ A,
                                                   const short* __restrict__ Bt,
                                                   const float* __restrict__ bias,
                                                   short* __restrict__ qo,
                                                   short* __restrict__ ko,
                                                   short* __restrict__ vt) {
  const int K = 1024;
  __shared__ short smem[24576];   // 2 x (A 8192 | B 4096); reused 16KB out-stage
  int tid = threadIdx.x;
  int ntile = blockIdx.x * 64, mtile = blockIdx.y * 128;
  int w = tid >> 6, l = tid & 63;
  int lr = l & 15, lg = l >> 4;

  f32x4 zero4 = {0.f, 0.f, 0.f, 0.f};
  f32x4 acc[2][4];
  #pragma unroll
  for (int i = 0; i < 2; ++i)
    #pragma unroll
    for (int j = 0; j < 4; ++j) acc[i][j] = zero4;

#define STAGE_QKV(BUF, K0) do {                                                      \
    short* Ab_ = smem + (BUF) * 12288;                                               \
    short* Bb_ = Ab_ + 8192;                                                         \
    _Pragma("unroll")                                                                \
    for (int c = 0; c < 4; ++c) {                                                    \
      int idx = tid + c * 256;                                                       \
      int row = idx >> 3, kc = idx & 7;                                              \
      gl_lds16(&A[(size_t)(mtile + row) * K + (K0) + kc * 8], &Ab_[idx * 8]);        \
    }                                                                                \
    _Pragma("unroll")                                                                \
    for (int c = 0; c < 2; ++c) {                                                    \
      int idx = tid + c * 256;                                                       \
      int row = idx >> 3, kc = idx & 7;                                              \
      gl_lds16(&Bt[(size_t)(ntile + row) * K + (K0) + kc * 8], &Bb_[idx * 8]);       \
    }                                                                                \
  } while (0)

  STAGE_QKV(0, 0);
  __syncthreads();
  int cur = 0;
  for (int it = 0; it < 16; ++it) {
    if (it < 15) STAGE_QKV(cur ^ 1, (it + 1) * 64);   // issue next tile early
    const short* Ab = smem + cur * 12288;
    const short* Bb = Ab + 8192;
    __builtin_amdgcn_s_setprio(1);
    #pragma unroll
    for (int kk = 0; kk < 2; ++kk) {
      bf16x8 af[2], bfr[4];
      #pragma unroll
      for (int i = 0; i < 2; ++i)
        af[i] = *reinterpret_cast<const bf16x8*>(&Ab[(w * 32 + i * 16 + lr) * 64 + kk * 32 + lg * 8]);
      #pragma unroll
      for (int j = 0; j < 4; ++j)
        bfr[j] = *reinterpret_cast<const bf16x8*>(&Bb[(j * 16 + lr) * 64 + kk * 32 + lg * 8]);
      #pragma unroll
      for (int i = 0; i < 2; ++i)
        #pragma unroll
        for (int j = 0; j < 4; ++j)
          acc[i][j] = __builtin_amdgcn_mfma_f32_16x16x32_bf16(af[i], bfr[j], acc[i][j], 0, 0, 0);
    }
    __builtin_amdgcn_s_setprio(0);
    __syncthreads();   // drains this iter's stage (vmcnt0) AFTER compute
    cur ^= 1;
  }
#undef STAGE_QKV

  // ---- epilogue: bias+scale+cvt -> LDS at final swizzled positions -> coalesced stores
  const int sec = ntile >> 10;   // 0=q 1=k 2=v (uniform per block)
  if (sec == 2) {
    #pragma unroll
    for (int j = 0; j < 4; ++j) {
      int d = j * 16 + lr;                  // within-head channel (block = one head)
      float bv = bias[ntile + d];
      #pragma unroll
      for (int i = 0; i < 2; ++i) {
        int lt0 = w * 32 + i * 16 + lg * 4; // r spans lt&7 consecutively
        int pos = (((lt0 >> 3) & 1) << 10) + (d & 31) * 32 +
                  ((((lt0 >> 4) & 1) + ((d >> 5) << 1)) << 3) + (lt0 & 7);
        short4 pk;
        pk.x = f2bf(acc[i][j][0] + bv);
        pk.y = f2bf(acc[i][j][1] + bv);
        pk.z = f2bf(acc[i][j][2] + bv);
        pk.w = f2bf(acc[i][j][3] + bv);
        *reinterpret_cast<short4*>(&smem[(lt0 >> 5) * 2048 + pos]) = pk;
      }
    }
  } else {
    // q scaled by (1/sqrt(64)) * log2(e) so attention works in exp2 domain
    const float sc = (sec == 0) ? 0.18033688f : 1.0f;
    #pragma unroll
    for (int j = 0; j < 4; ++j) {
      int d = j * 16 + lr;
      float bv = bias[ntile + d];
      int dpart = (((d >> 3) & 1) << 10) + ((d >> 4) << 3) + (d & 7);
      #pragma unroll
      for (int i = 0; i < 2; ++i) {
        #pragma unroll
        for (int r = 0; r < 4; ++r) {
          int lt = w * 32 + i * 16 + lg * 4 + r;
          smem[(lt >> 5) * 2048 + (lt & 31) * 32 + dpart] = f2bf((acc[i][j][r] + bv) * sc);
        }
      }
    }
  }
  __syncthreads();
  short* dst = (sec == 0) ? qo : ((sec == 1) ? ko : vt);
  int bb  = mtile >> 11;
  int h0  = (ntile & 1023) >> 6;
  int gt0 = (mtile & 2047) >> 5;
  #pragma unroll
  for (int c2 = 0; c2 < 4; ++c2) {
    size_t base = (size_t)(bb * 16 + h0) * 131072 + (size_t)(gt0 + c2) * 2048;
    *reinterpret_cast<uint4*>(&dst[base + tid * 8]) =
        *reinterpret_cast<const uint4*>(&smem[c2 * 2048 + tid * 8]);
  }
}

// ---- flash attention v14: fragment-swizzled Q/K/V -> every global load is
//      lane-contiguous 64B (8 lines/instr). kv-split + two-pass merge. ----
template<int DIAG>
__device__ __forceinline__ void attn_step(const short* __restrict__ kp,
                                          const short* __restrict__ vp,
                                          const bf16x8* qf,
                                          f32x16& y0, f32x16& y1,
                                          float& m, float& li,
                                          int lq, int hl) {
  f32x16 s;
  #pragma unroll
  for (int r = 0; r < 16; ++r) s[r] = 0.f;
  __builtin_amdgcn_s_setprio(1);
  #pragma unroll
  for (int ks = 0; ks < 4; ++ks) {
    bf16x8 kf = *reinterpret_cast<const bf16x8*>(kp + ks * 8);
    s = __builtin_amdgcn_mfma_f32_32x32x16_bf16(kf, qf[ks], s, 0, 0, 0);
  }
  __builtin_amdgcn_s_setprio(0);
  if (DIAG) {
    #pragma unroll
    for (int r = 0; r < 16; ++r) {
      int kvl = (r & 3) + 8 * (r >> 2) + 4 * hl;
      if (kvl > lq) s[r] = -1e30f;
    }
  }
  float a0 = fmaxf(fmaxf(s[0], s[1]), fmaxf(s[2], s[3]));
  float a1 = fmaxf(fmaxf(s[4], s[5]), fmaxf(s[6], s[7]));
  float a2 = fmaxf(fmaxf(s[8], s[9]), fmaxf(s[10], s[11]));
  float a3 = fmaxf(fmaxf(s[12], s[13]), fmaxf(s[14], s[15]));
  float pm = fmaxf(fmaxf(a0, a1), fmaxf(a2, a3));
  pm = fmaxf(pm, __shfl_xor(pm, 32));
  if (!__all(pm - m <= 8.0f)) {
    float mn = fmaxf(m, pm);
    float sc = __builtin_amdgcn_exp2f(m - mn);
    m = mn;
    li *= sc;
    #pragma unroll
    for (int r = 0; r < 16; ++r) { y0[r] *= sc; y1[r] *= sc; }
  }
  unsigned u[8];
  float rs = 0.f;
  #pragma unroll
  for (int rq = 0; rq < 4; ++rq) {
    float p0 = __builtin_amdgcn_exp2f(s[4 * rq + 0] - m);
    float p1 = __builtin_amdgcn_exp2f(s[4 * rq + 1] - m);
    float p2 = __builtin_amdgcn_exp2f(s[4 * rq + 2] - m);
    float p3 = __builtin_amdgcn_exp2f(s[4 * rq + 3] - m);
    rs += (p0 + p1) + (p2 + p3);
    asm("v_cvt_pk_bf16_f32 %0, %1, %2" : "=v"(u[rq * 2 + 0]) : "v"(p0), "v"(p1));
    asm("v_cvt_pk_bf16_f32 %0, %1, %2" : "=v"(u[rq * 2 + 1]) : "v"(p2), "v"(p3));
  }
  rs += __shfl_xor(rs, 32);
  li += rs;
  asm volatile("v_permlane32_swap_b32 %0, %1" : "+v"(u[0]), "+v"(u[2]));
  asm volatile("v_permlane32_swap_b32 %0, %1" : "+v"(u[1]), "+v"(u[3]));
  asm volatile("v_permlane32_swap_b32 %0, %1" : "+v"(u[4]), "+v"(u[6]));
  asm volatile("v_permlane32_swap_b32 %0, %1" : "+v"(u[5]), "+v"(u[7]));
  uint32x4 w0 = {u[0], u[1], u[2], u[3]};
  uint32x4 w1 = {u[4], u[5], u[6], u[7]};
  bf16x8 pa0 = __builtin_bit_cast(bf16x8, w0);
  bf16x8 pa1 = __builtin_bit_cast(bf16x8, w1);
  __builtin_amdgcn_s_setprio(1);
  {
    bf16x8 vf00 = *reinterpret_cast<const bf16x8*>(vp);
    bf16x8 vf01 = *reinterpret_cast<const bf16x8*>(vp + 8);
    bf16x8 vf10 = *reinterpret_cast<const bf16x8*>(vp + 16);
    bf16x8 vf11 = *reinterpret_cast<const bf16x8*>(vp + 24);
    y0 = __builtin_amdgcn_mfma_f32_32x32x16_bf16(vf00, pa0, y0, 0, 0, 0);
    y0 = __builtin_amdgcn_mfma_f32_32x32x16_bf16(vf01, pa1, y0, 0, 0, 0);
    y1 = __builtin_amdgcn_mfma_f32_32x32x16_bf16(vf10, pa0, y1, 0, 0, 0);
    y1 = __builtin_amdgcn_mfma_f32_32x32x16_bf16(vf11, pa1, y1, 0, 0, 0);
  }
  __builtin_amdgcn_s_setprio(0);
}

__global__ __launch_bounds__(256, 4) void attn_kernel(const short* __restrict__ q,
                                                      const short* __restrict__ k,
                                                      const short* __restrict__ vt,
                                                      short* __restrict__ y) {
  __shared__ float partL[3][4][64][4];   // 12 KB, reused for y0 then y1 pass
  __shared__ float stm[4][32], stl[4][32];
  const int bid = blockIdx.x;
  const int t = 63 - (bid >> 5);           // longest-first
  const int b5 = bid & 31;
  const int bh = (b5 & 7) * 4 + (b5 >> 3); // group each bh's blocks on one XCD
  const int tid = threadIdx.x;
  const int w = tid >> 6;                  // wave: kv-split index 0..3
  const int l = tid & 63;
  const int lq = l & 31, hl = l >> 5;
  const short* qb = q + (size_t)bh * 131072;
  const short* kb = k + (size_t)bh * 131072;
  const short* vb = vt + (size_t)bh * 131072;

  // Q fragments: swizzled -> one coalesced 64B read per lane
  bf16x8 qf[4];
  {
    const short* qp = qb + (size_t)t * 2048 + l * 32;
    #pragma unroll
    for (int ks = 0; ks < 4; ++ks)
      qf[ks] = *reinterpret_cast<const bf16x8*>(qp + ks * 8);
  }

  f32x16 y0, y1;
  #pragma unroll
  for (int r = 0; r < 16; ++r) { y0[r] = 0.f; y1[r] = 0.f; }
  float m = -1e30f, li = 0.f;

  // wave w handles kv tiles {w, w+4, ...} < t, plus diag tile t if t&3==w
  const short* kp = kb + (size_t)w * 2048 + l * 32;
  const short* vp = vb + (size_t)w * 2048 + l * 32;
  for (int it = w; it < t; it += 4) {
    attn_step<0>(kp, vp, qf, y0, y1, m, li, lq, hl);
    kp += 4 * 2048;
    vp += 4 * 2048;
  }
  if ((t & 3) == w) {
    const short* kpd = kb + (size_t)t * 2048 + l * 32;
    const short* vpd = vb + (size_t)t * 2048 + l * 32;
    attn_step<1>(kpd, vpd, qf, y0, y1, m, li, lq, hl);
  }

  // ---- merge the 4 wave-partials (two passes over a half-size buffer) ----
  if (hl == 0) { stm[w][lq] = m; stl[w][lq] = li; }
  __syncthreads();
  float m0 = stm[0][lq], m1 = stm[1][lq], m2 = stm[2][lq], m3 = stm[3][lq];
  float M = fmaxf(fmaxf(m0, m1), fmaxf(m2, m3));
  float L = stl[0][lq] * __builtin_amdgcn_exp2f(m0 - M) +
            stl[1][lq] * __builtin_amdgcn_exp2f(m1 - M) +
            stl[2][lq] * __builtin_amdgcn_exp2f(m2 - M) +
            stl[3][lq] * __builtin_amdgcn_exp2f(m3 - M);
  float sc = __builtin_amdgcn_exp2f(m - M);
  #pragma unroll
  for (int r = 0; r < 16; ++r) { y0[r] *= sc; y1[r] *= sc; }

  // pass 0: merge y0
  if (w > 0) {
    #pragma unroll
    for (int c = 0; c < 4; ++c) {
      f32x4 v0 = {y0[4 * c + 0], y0[4 * c + 1], y0[4 * c + 2], y0[4 * c + 3]};
      *reinterpret_cast<f32x4*>(&partL[w - 1][c][l][0]) = v0;
    }
  }
  __syncthreads();
  if (w == 0) {
    #pragma unroll
    for (int o = 0; o < 3; ++o)
      #pragma unroll
      for (int c = 0; c < 4; ++c) {
        f32x4 v0 = *reinterpret_cast<const f32x4*>(&partL[o][c][l][0]);
        #pragma unroll
        for (int r = 0; r < 4; ++r) y0[4 * c + r] += v0[r];
      }
  }
  __syncthreads();
  // pass 1: merge y1 (buffer reused)
  if (w > 0) {
    #pragma unroll
    for (int c = 0; c < 4; ++c) {
      f32x4 v1 = {y1[4 * c + 0], y1[4 * c + 1], y1[4 * c + 2], y1[4 * c + 3]};
      *reinterpret_cast<f32x4*>(&partL[w - 1][c][l][0]) = v1;
    }
  }
  __syncthreads();
  if (w == 0) {
    #pragma unroll
    for (int o = 0; o < 3; ++o)
      #pragma unroll
      for (int c = 0; c < 4; ++c) {
        f32x4 v1 = *reinterpret_cast<const f32x4*>(&partL[o][c][l][0]);
        #pragma unroll
        for (int r = 0; r < 4; ++r) y1[4 * c + r] += v1[r];
      }
    float inv = 1.0f / L;
    int b_ = bh >> 4, h_ = bh & 15;
    short* yrow = &y[(size_t)(b_ * 2048 + 32 * t + lq) * 1024 + h_ * 64];
    #pragma unroll
    for (int dt = 0; dt < 2; ++dt) {
      const f32x16& yy = dt ? y1 : y0;
      #pragma unroll
      for (int rq = 0; rq < 4; ++rq) {
        int d0 = dt * 32 + 8 * rq + 4 * hl;
        uint2 pk;
        pk.x = (unsigned)(unsigned short)f2bf(yy[4 * rq + 0] * inv) |
               ((unsigned)(unsigned short)f2bf(yy[4 * rq + 1] * inv) << 16);
        pk.y = (unsigned)(unsigned short)f2bf(yy[4 * rq + 2] * inv) |
               ((unsigned)(unsigned short)f2bf(yy[4 * rq + 3] * inv) << 16);
        *reinterpret_cast<uint2*>(yrow + d0) = pk;
      }
    }
  }
}

// ---- GEMM3 v3: BM=128 x BN=64, 2-phase double-buffered pipeline ----
__global__ __launch_bounds__(256, 3) void gemm_proj(const short* __restrict__ A,
                                                    const short* __restrict__ Bt,
                                                    const float* __restrict__ bias,
                                                    float* __restrict__ out) {
  const int K = 1024;
  __shared__ short smem[24576];   // 2 x (A 8192 | B 4096)
  int tid = threadIdx.x;
  int ntile = blockIdx.x * 64, mtile = blockIdx.y * 128;
  int w = tid >> 6, l = tid & 63;
  int lr = l & 15, lg = l >> 4;

  f32x4 zero4 = {0.f, 0.f, 0.f, 0.f};
  f32x4 acc[2][4];
  #pragma unroll
  for (int i = 0; i < 2; ++i)
    #pragma unroll
    for (int j = 0; j < 4; ++j) acc[i][j] = zero4;

#define STAGE_PRJ(BUF, K0) do {                                                      \
    short* Ab_ = smem + (BUF) * 12288;                                               \
    short* Bb_ = Ab_ + 8192;                                                         \
    _Pragma("unroll")                                                                \
    for (int c = 0; c < 4; ++c) {                                                    \
      int idx = tid + c * 256;                                                       \
      int row = idx >> 3, kc = idx & 7;                                              \
      gl_lds16(&A[(size_t)(mtile + row) * K + (K0) + kc * 8], &Ab_[idx * 8]);        \
    }                                                                                \
    _Pragma("unroll")                                                                \
    for (int c = 0; c < 2; ++c) {                                                    \
      int idx = tid + c * 256;                                                       \
      int row = idx >> 3, kc = idx & 7;                                              \
      gl_lds16(&Bt[(size_t)(ntile + row) * K + (K0) + kc * 8], &Bb_[idx * 8]);       \
    }                                                                                \
  } while (0)

  STAGE_PRJ(0, 0);
  __syncthreads();
  int cur = 0;
  for (int it = 0; it < 16; ++it) {
    if (it < 15) STAGE_PRJ(cur ^ 1, (it + 1) * 64);
    const short* Ab = smem + cur * 12288;
    const short* Bb = Ab + 8192;
    __builtin_amdgcn_s_setprio(1);
    #pragma unroll
    for (int kk = 0; kk < 2; ++kk) {
      bf16x8 af[2], bfr[4];
      #pragma unroll
      for (int i = 0; i < 2; ++i)
        af[i] = *reinterpret_cast<const bf16x8*>(&Ab[(w * 32 + i * 16 + lr) * 64 + kk * 32 + lg * 8]);
      #pragma unroll
      for (int j = 0; j < 4; ++j)
        bfr[j] = *reinterpret_cast<const bf16x8*>(&Bb[(j * 16 + lr) * 64 + kk * 32 + lg * 8]);
      #pragma unroll
      for (int i = 0; i < 2; ++i)
        #pragma unroll
        for (int j = 0; j < 4; ++j)
          acc[i][j] = __builtin_amdgcn_mfma_f32_16x16x32_bf16(af[i], bfr[j], acc[i][j], 0, 0, 0);
    }
    __builtin_amdgcn_s_setprio(0);
    __syncthreads();
    cur ^= 1;
  }
#undef STAGE_PRJ

  #pragma unroll
  for (int j = 0; j < 4; ++j) {
    int n = ntile + j * 16 + lr;
    float bv = bias[n];
    #pragma unroll
    for (int i = 0; i < 2; ++i) {
      #pragma unroll
      for (int r = 0; r < 4; ++r) {
        int m = mtile + w * 32 + i * 16 + lg * 4 + r;
        out[(size_t)m * 1024 + n] = acc[i][j][r] + bv;
      }
    }
  }
}

extern "C" void kernel_launch(void* const* d_in, const int* in_sizes, int n_in,
                              void* d_out, int out_size, void* d_ws, size_t ws_size,
                              hipStream_t stream) {
  const float* x     = (const float*)d_in[0];
  const float* Wqkv  = (const float*)d_in[1];
  const float* bqkv  = (const float*)d_in[2];
  const float* Wproj = (const float*)d_in[3];
  const float* bproj = (const float*)d_in[4];
  float* out = (float*)d_out;

  const size_t M4 = 4096ull * 1024ull;
  short* ws = (short*)d_ws;
  short* x_bf    = ws;
  short* wqkv_t  = ws + M4;
  short* wproj_t = ws + M4 + 3ull * 1024 * 1024;
  short* qb      = wproj_t + 1024ull * 1024;
  short* kb      = qb + M4;
  short* vtb     = kb + M4;     // fragment-swizzled V^T
  short* yb      = x_bf;        // alias: x_bf dead after gemm_qkv

  cast_x_kernel<<<4096, 256, 0, stream>>>(x, x_bf, (int)(M4 / 4));
  transpose_cast<<<dim3(48, 16), 256, 0, stream>>>(Wqkv, wqkv_t, 1024, 3072);
  transpose_cast<<<dim3(16, 16), 256, 0, stream>>>(Wproj, wproj_t, 1024, 1024);
  gemm_qkv<<<dim3(48, 32), 256, 0, stream>>>(x_bf, wqkv_t, bqkv, qb, kb, vtb);
  attn_kernel<<<2048, 256, 0, stream>>>(qb, kb, vtb, yb);
  gemm_proj<<<dim3(16, 32), 256, 0, stream>>>(yb, wproj_t, bproj, out);
}

// Round 18
// 120.161 us; speedup vs baseline: 1.4016x; 1.0158x over previous
//
#include <hip/hip_runtime.h>

// ---- types ----
typedef __bf16 bf16x8 __attribute__((ext_vector_type(8)));
typedef float  f32x4  __attribute__((ext_vector_type(4)));
typedef float  f32x16 __attribute__((ext_vector_type(16)));
typedef unsigned int uint32x4 __attribute__((ext_vector_type(4)));

__device__ __forceinline__ short f2bf(float f) {
  union { float f; unsigned u; } v; v.f = f;
  unsigned r = v.u + 0x7fffu + ((v.u >> 16) & 1u);
  return (short)(r >> 16);
}

// async global->LDS (16B per lane); LDS dest must be wave-uniform base + lane*16
__device__ __forceinline__ void gl_lds16(const short* g, short* l) {
  __builtin_amdgcn_global_load_lds((const __attribute__((address_space(1))) void*)g,
                                   (__attribute__((address_space(3))) void*)l, 16, 0, 0);
}

// ---- cast x fp32 -> bf16 (vectorized) ----
__global__ __launch_bounds__(256) void cast_x_kernel(const float* __restrict__ in,
                                                     short* __restrict__ out, int n4) {
  int i = blockIdx.x * 256 + threadIdx.x;
  if (i >= n4) return;
  float4 f = reinterpret_cast<const float4*>(in)[i];
  short4 o;
  o.x = f2bf(f.x); o.y = f2bf(f.y); o.z = f2bf(f.z); o.w = f2bf(f.w);
  reinterpret_cast<short4*>(out)[i] = o;
}

// ---- transpose + cast: in[R][Cc] fp32 -> out[Cc][R] bf16 ----
__global__ __launch_bounds__(256) void transpose_cast(const float* __restrict__ in,
                                                      short* __restrict__ out, int R, int Cc) {
  __shared__ short tile[64][65];
  int bx = blockIdx.x * 64;
  int by = blockIdx.y * 64;
  int tx = threadIdx.x & 63, ty = threadIdx.x >> 6;
  #pragma unroll
  for (int i = ty; i < 64; i += 4)
    tile[i][tx] = f2bf(in[(size_t)(by + i) * Cc + bx + tx]);
  __syncthreads();
  #pragma unroll
  for (int i = ty; i < 64; i += 4)
    out[(size_t)(bx + i) * R + by + tx] = tile[tx][i];
}

// ==== swizzled fragment layouts (per bh, 64 tiles x 2048 shorts) ====
// Q/K: (t,d) -> (t>>5)*2048 + (((d>>3)&1)<<10) + (t&31)*32 + ((d>>4)<<3) + (d&7)
// V^T: (d,t) -> (t>>5)*2048 + (((t>>3)&1)<<10) + (d&31)*32
//               + ((((t>>4)&1)+((d>>5)<<1))<<3) + (t&7)

// ---- GEMM1 v5: BM=BN=128 (32 MFMA per 8 staged loads), 2-phase double buffer,
//      XCD-chunked swizzle (each XCD owns 3 ntile cols -> B panel L2-resident),
//      LDS-staged coalesced epilogue into fragment-swizzled q/k/V^T ----
__global__ __launch_bounds__(256, 2) void gemm_qkv(const short* __restrict__ A,
                                                   const short* __restrict__ Bt,
                                                   const float* __restrict__ bias,
                                                   short* __restrict__ qo,
                                                   short* __restrict__ ko,
                                                   short* __restrict__ vt) {
  const int K = 1024;
  __shared__ short smem[32768];   // 2 x (A 8192 | B 8192); epilogue reuses first 16384
  int tid = threadIdx.x;
  // XCD swizzle: bid&7 = XCD; each XCD owns ntile cols [x*3, x*3+3)
  int x = blockIdx.x & 7, r = blockIdx.x >> 3;   // r in [0,96)
  int mt = r / 3, ntl = r - mt * 3;
  int ntile = (x * 3 + ntl) * 128, mtile = mt * 128;
  int w = tid >> 6, l = tid & 63;
  int wr = w >> 1, wc = w & 1;
  int lr = l & 15, lg = l >> 4;

  f32x4 zero4 = {0.f, 0.f, 0.f, 0.f};
  f32x4 acc[4][4];
  #pragma unroll
  for (int i = 0; i < 4; ++i)
    #pragma unroll
    for (int j = 0; j < 4; ++j) acc[i][j] = zero4;

#define STAGE_QKV(BUF, K0) do {                                                      \
    short* Ab_ = smem + (BUF) * 16384;                                               \
    short* Bb_ = Ab_ + 8192;                                                         \
    _Pragma("unroll")                                                                \
    for (int c = 0; c < 4; ++c) {                                                    \
      int idx = tid + c * 256;                                                       \
      int row = idx >> 3, kc = idx & 7;                                              \
      gl_lds16(&A[(size_t)(mtile + row) * K + (K0) + kc * 8], &Ab_[idx * 8]);        \
      gl_lds16(&Bt[(size_t)(ntile + row) * K + (K0) + kc * 8], &Bb_[idx * 8]);       \
    }                                                                                \
  } while (0)

  STAGE_QKV(0, 0);
  __syncthreads();
  int cur = 0;
  for (int it = 0; it < 16; ++it) {
    if (it < 15) STAGE_QKV(cur ^ 1, (it + 1) * 64);   // issue next tile early
    const short* Ab = smem + cur * 16384;
    const short* Bb = Ab + 8192;
    __builtin_amdgcn_s_setprio(1);
    #pragma unroll
    for (int kk = 0; kk < 2; ++kk) {
      bf16x8 af[4], bfr[4];
      #pragma unroll
      for (int i = 0; i < 4; ++i)
        af[i] = *reinterpret_cast<const bf16x8*>(&Ab[(wr * 64 + i * 16 + lr) * 64 + kk * 32 + lg * 8]);
      #pragma unroll
      for (int j = 0; j < 4; ++j)
        bfr[j] = *reinterpret_cast<const bf16x8*>(&Bb[(wc * 64 + j * 16 + lr) * 64 + kk * 32 + lg * 8]);
      #pragma unroll
      for (int i = 0; i < 4; ++i)
        #pragma unroll
        for (int j = 0; j < 4; ++j)
          acc[i][j] = __builtin_amdgcn_mfma_f32_16x16x32_bf16(af[i], bfr[j], acc[i][j], 0, 0, 0);
    }
    __builtin_amdgcn_s_setprio(0);
    __syncthreads();   // drains this iter's stage AFTER compute
    cur ^= 1;
  }
#undef STAGE_QKV

  // ---- epilogue: bias+scale+cvt -> LDS at final swizzled positions -> coalesced stores
  const int sec = ntile >> 10;   // 0=q 1=k 2=v (uniform per block)
  if (sec == 2) {
    #pragma unroll
    for (int j = 0; j < 4; ++j) {
      int nl = wc * 64 + j * 16 + lr;        // [0,128): spans 2 heads
      int d  = nl & 63;
      float bv = bias[ntile + nl];
      #pragma unroll
      for (int i = 0; i < 4; ++i) {
        int lt0 = wr * 64 + i * 16 + lg * 4; // r spans lt&7 consecutively
        int c2 = (nl >> 6) * 4 + (lt0 >> 5);
        int pos = (((lt0 >> 3) & 1) << 10) + (d & 31) * 32 +
                  ((((lt0 >> 4) & 1) + ((d >> 5) << 1)) << 3) + (lt0 & 7);
        short4 pk;
        pk.x = f2bf(acc[i][j][0] + bv);
        pk.y = f2bf(acc[i][j][1] + bv);
        pk.z = f2bf(acc[i][j][2] + bv);
        pk.w = f2bf(acc[i][j][3] + bv);
        *reinterpret_cast<short4*>(&smem[c2 * 2048 + pos]) = pk;
      }
    }
  } else {
    // q scaled by (1/sqrt(64)) * log2(e) so attention works in exp2 domain
    const float sc = (sec == 0) ? 0.18033688f : 1.0f;
    #pragma unroll
    for (int j = 0; j < 4; ++j) {
      int nl = wc * 64 + j * 16 + lr;
      int d  = nl & 63;
      float bv = bias[ntile + nl];
      int dpart = (((d >> 3) & 1) << 10) + ((d >> 4) << 3) + (d & 7);
      #pragma unroll
      for (int i = 0; i < 4; ++i) {
        #pragma unroll
        for (int r2 = 0; r2 < 4; ++r2) {
          int lt = wr * 64 + i * 16 + lg * 4 + r2;
          int c2 = (nl >> 6) * 4 + (lt >> 5);
          smem[c2 * 2048 + (lt & 31) * 32 + dpart] = f2bf((acc[i][j][r2] + bv) * sc);
        }
      }
    }
  }
  __syncthreads();
  short* dst = (sec == 0) ? qo : ((sec == 1) ? ko : vt);
  int bb  = mtile >> 11;
  int h0  = (ntile & 1023) >> 6;
  int gt0 = (mtile & 2047) >> 5;
  #pragma unroll
  for (int c2 = 0; c2 < 8; ++c2) {
    size_t base = (size_t)(bb * 16 + h0 + (c2 >> 2)) * 131072 +
                  (size_t)(gt0 + (c2 & 3)) * 2048;
    *reinterpret_cast<uint4*>(&dst[base + tid * 8]) =
        *reinterpret_cast<const uint4*>(&smem[c2 * 2048 + tid * 8]);
  }
}

// ---- flash attention v14: fragment-swizzled Q/K/V -> every global load is
//      lane-contiguous 64B (8 lines/instr). kv-split + two-pass merge. ----
template<int DIAG>
__device__ __forceinline__ void attn_step(const short* __restrict__ kp,
                                          const short* __restrict__ vp,
                                          const bf16x8* qf,
                                          f32x16& y0, f32x16& y1,
                                          float& m, float& li,
                                          int lq, int hl) {
  f32x16 s;
  #pragma unroll
  for (int r = 0; r < 16; ++r) s[r] = 0.f;
  __builtin_amdgcn_s_setprio(1);
  #pragma unroll
  for (int ks = 0; ks < 4; ++ks) {
    bf16x8 kf = *reinterpret_cast<const bf16x8*>(kp + ks * 8);
    s = __builtin_amdgcn_mfma_f32_32x32x16_bf16(kf, qf[ks], s, 0, 0, 0);
  }
  __builtin_amdgcn_s_setprio(0);
  if (DIAG) {
    #pragma unroll
    for (int r = 0; r < 16; ++r) {
      int kvl = (r & 3) + 8 * (r >> 2) + 4 * hl;
      if (kvl > lq) s[r] = -1e30f;
    }
  }
  float a0 = fmaxf(fmaxf(s[0], s[1]), fmaxf(s[2], s[3]));
  float a1 = fmaxf(fmaxf(s[4], s[5]), fmaxf(s[6], s[7]));
  float a2 = fmaxf(fmaxf(s[8], s[9]), fmaxf(s[10], s[11]));
  float a3 = fmaxf(fmaxf(s[12], s[13]), fmaxf(s[14], s[15]));
  float pm = fmaxf(fmaxf(a0, a1), fmaxf(a2, a3));
  pm = fmaxf(pm, __shfl_xor(pm, 32));
  if (!__all(pm - m <= 8.0f)) {
    float mn = fmaxf(m, pm);
    float sc = __builtin_amdgcn_exp2f(m - mn);
    m = mn;
    li *= sc;
    #pragma unroll
    for (int r = 0; r < 16; ++r) { y0[r] *= sc; y1[r] *= sc; }
  }
  unsigned u[8];
  float rs = 0.f;
  #pragma unroll
  for (int rq = 0; rq < 4; ++rq) {
    float p0 = __builtin_amdgcn_exp2f(s[4 * rq + 0] - m);
    float p1 = __builtin_amdgcn_exp2f(s[4 * rq + 1] - m);
    float p2 = __builtin_amdgcn_exp2f(s[4 * rq + 2] - m);
    float p3 = __builtin_amdgcn_exp2f(s[4 * rq + 3] - m);
    rs += (p0 + p1) + (p2 + p3);
    asm("v_cvt_pk_bf16_f32 %0, %1, %2" : "=v"(u[rq * 2 + 0]) : "v"(p0), "v"(p1));
    asm("v_cvt_pk_bf16_f32 %0, %1, %2" : "=v"(u[rq * 2 + 1]) : "v"(p2), "v"(p3));
  }
  rs += __shfl_xor(rs, 32);
  li += rs;
  asm volatile("v_permlane32_swap_b32 %0, %1" : "+v"(u[0]), "+v"(u[2]));
  asm volatile("v_permlane32_swap_b32 %0, %1" : "+v"(u[1]), "+v"(u[3]));
  asm volatile("v_permlane32_swap_b32 %0, %1" : "+v"(u[4]), "+v"(u[6]));
  asm volatile("v_permlane32_swap_b32 %0, %1" : "+v"(u[5]), "+v"(u[7]));
  uint32x4 w0 = {u[0], u[1], u[2], u[3]};
  uint32x4 w1 = {u[4], u[5], u[6], u[7]};
  bf16x8 pa0 = __builtin_bit_cast(bf16x8, w0);
  bf16x8 pa1 = __builtin_bit_cast(bf16x8, w1);
  __builtin_amdgcn_s_setprio(1);
  {
    bf16x8 vf00 = *reinterpret_cast<const bf16x8*>(vp);
    bf16x8 vf01 = *reinterpret_cast<const bf16x8*>(vp + 8);
    bf16x8 vf10 = *reinterpret_cast<const bf16x8*>(vp + 16);
    bf16x8 vf11 = *reinterpret_cast<const bf16x8*>(vp + 24);
    y0 = __builtin_amdgcn_mfma_f32_32x32x16_bf16(vf00, pa0, y0, 0, 0, 0);
    y0 = __builtin_amdgcn_mfma_f32_32x32x16_bf16(vf01, pa1, y0, 0, 0, 0);
    y1 = __builtin_amdgcn_mfma_f32_32x32x16_bf16(vf10, pa0, y1, 0, 0, 0);
    y1 = __builtin_amdgcn_mfma_f32_32x32x16_bf16(vf11, pa1, y1, 0, 0, 0);
  }
  __builtin_amdgcn_s_setprio(0);
}

__global__ __launch_bounds__(256, 4) void attn_kernel(const short* __restrict__ q,
                                                      const short* __restrict__ k,
                                                      const short* __restrict__ vt,
                                                      short* __restrict__ y) {
  __shared__ float partL[3][4][64][4];   // 12 KB, reused for y0 then y1 pass
  __shared__ float stm[4][32], stl[4][32];
  const int bid = blockIdx.x;
  const int t = 63 - (bid >> 5);           // longest-first
  const int b5 = bid & 31;
  const int bh = (b5 & 7) * 4 + (b5 >> 3); // group each bh's blocks on one XCD
  const int tid = threadIdx.x;
  const int w = tid >> 6;                  // wave: kv-split index 0..3
  const int l = tid & 63;
  const int lq = l & 31, hl = l >> 5;
  const short* qb = q + (size_t)bh * 131072;
  const short* kb = k + (size_t)bh * 131072;
  const short* vb = vt + (size_t)bh * 131072;

  // Q fragments: swizzled -> one coalesced 64B read per lane
  bf16x8 qf[4];
  {
    const short* qp = qb + (size_t)t * 2048 + l * 32;
    #pragma unroll
    for (int ks = 0; ks < 4; ++ks)
      qf[ks] = *reinterpret_cast<const bf16x8*>(qp + ks * 8);
  }

  f32x16 y0, y1;
  #pragma unroll
  for (int r = 0; r < 16; ++r) { y0[r] = 0.f; y1[r] = 0.f; }
  float m = -1e30f, li = 0.f;

  // wave w handles kv tiles {w, w+4, ...} < t, plus diag tile t if t&3==w
  const short* kp = kb + (size_t)w * 2048 + l * 32;
  const short* vp = vb + (size_t)w * 2048 + l * 32;
  for (int it = w; it < t; it += 4) {
    attn_step<0>(kp, vp, qf, y0, y1, m, li, lq, hl);
    kp += 4 * 2048;
    vp += 4 * 2048;
  }
  if ((t & 3) == w) {
    const short* kpd = kb + (size_t)t * 2048 + l * 32;
    const short* vpd = vb + (size_t)t * 2048 + l * 32;
    attn_step<1>(kpd, vpd, qf, y0, y1, m, li, lq, hl);
  }

  // ---- merge the 4 wave-partials (two passes over a half-size buffer) ----
  if (hl == 0) { stm[w][lq] = m; stl[w][lq] = li; }
  __syncthreads();
  float m0 = stm[0][lq], m1 = stm[1][lq], m2 = stm[2][lq], m3 = stm[3][lq];
  float M = fmaxf(fmaxf(m0, m1), fmaxf(m2, m3));
  float L = stl[0][lq] * __builtin_amdgcn_exp2f(m0 - M) +
            stl[1][lq] * __builtin_amdgcn_exp2f(m1 - M) +
            stl[2][lq] * __builtin_amdgcn_exp2f(m2 - M) +
            stl[3][lq] * __builtin_amdgcn_exp2f(m3 - M);
  float sc = __builtin_amdgcn_exp2f(m - M);
  #pragma unroll
  for (int r = 0; r < 16; ++r) { y0[r] *= sc; y1[r] *= sc; }

  // pass 0: merge y0
  if (w > 0) {
    #pragma unroll
    for (int c = 0; c < 4; ++c) {
      f32x4 v0 = {y0[4 * c + 0], y0[4 * c + 1], y0[4 * c + 2], y0[4 * c + 3]};
      *reinterpret_cast<f32x4*>(&partL[w - 1][c][l][0]) = v0;
    }
  }
  __syncthreads();
  if (w == 0) {
    #pragma unroll
    for (int o = 0; o < 3; ++o)
      #pragma unroll
      for (int c = 0; c < 4; ++c) {
        f32x4 v0 = *reinterpret_cast<const f32x4*>(&partL[o][c][l][0]);
        #pragma unroll
        for (int r = 0; r < 4; ++r) y0[4 * c + r] += v0[r];
      }
  }
  __syncthreads();
  // pass 1: merge y1 (buffer reused)
  if (w > 0) {
    #pragma unroll
    for (int c = 0; c < 4; ++c) {
      f32x4 v1 = {y1[4 * c + 0], y1[4 * c + 1], y1[4 * c + 2], y1[4 * c + 3]};
      *reinterpret_cast<f32x4*>(&partL[w - 1][c][l][0]) = v1;
    }
  }
  __syncthreads();
  if (w == 0) {
    #pragma unroll
    for (int o = 0; o < 3; ++o)
      #pragma unroll
      for (int c = 0; c < 4; ++c) {
        f32x4 v1 = *reinterpret_cast<const f32x4*>(&partL[o][c][l][0]);
        #pragma unroll
        for (int r = 0; r < 4; ++r) y1[4 * c + r] += v1[r];
      }
    float inv = 1.0f / L;
    int b_ = bh >> 4, h_ = bh & 15;
    short* yrow = &y[(size_t)(b_ * 2048 + 32 * t + lq) * 1024 + h_ * 64];
    #pragma unroll
    for (int dt = 0; dt < 2; ++dt) {
      const f32x16& yy = dt ? y1 : y0;
      #pragma unroll
      for (int rq = 0; rq < 4; ++rq) {
        int d0 = dt * 32 + 8 * rq + 4 * hl;
        uint2 pk;
        pk.x = (unsigned)(unsigned short)f2bf(yy[4 * rq + 0] * inv) |
               ((unsigned)(unsigned short)f2bf(yy[4 * rq + 1] * inv) << 16);
        pk.y = (unsigned)(unsigned short)f2bf(yy[4 * rq + 2] * inv) |
               ((unsigned)(unsigned short)f2bf(yy[4 * rq + 3] * inv) << 16);
        *reinterpret_cast<uint2*>(yrow + d0) = pk;
      }
    }
  }
}

// ---- GEMM3 v4: BM=128 x BN=64, 2-phase double buffer + XCD swizzle ----
__global__ __launch_bounds__(256, 3) void gemm_proj(const short* __restrict__ A,
                                                    const short* __restrict__ Bt,
                                                    const float* __restrict__ bias,
                                                    float* __restrict__ out) {
  const int K = 1024;
  __shared__ short smem[24576];   // 2 x (A 8192 | B 4096)
  int tid = threadIdx.x;
  // XCD swizzle: each XCD owns 2 ntile cols (256 KB B panel, L2-resident)
  int x = blockIdx.x & 7, r = blockIdx.x >> 3;  // r in [0,64)
  int ntile = (x * 2 + (r & 1)) * 64, mtile = (r >> 1) * 128;
  int w = tid >> 6, l = tid & 63;
  int lr = l & 15, lg = l >> 4;

  f32x4 zero4 = {0.f, 0.f, 0.f, 0.f};
  f32x4 acc[2][4];
  #pragma unroll
  for (int i = 0; i < 2; ++i)
    #pragma unroll
    for (int j = 0; j < 4; ++j) acc[i][j] = zero4;

#define STAGE_PRJ(BUF, K0) do {                                                      \
    short* Ab_ = smem + (BUF) * 12288;                                               \
    short* Bb_ = Ab_ + 8192;                                                         \
    _Pragma("unroll")                                                                \
    for (int c = 0; c < 4; ++c) {                                                    \
      int idx = tid + c * 256;                                                       \
      int row = idx >> 3, kc = idx & 7;                                              \
      gl_lds16(&A[(size_t)(mtile + row) * K + (K0) + kc * 8], &Ab_[idx * 8]);        \
    }                                                                                \
    _Pragma("unroll")                                                                \
    for (int c = 0; c < 2; ++c) {                                                    \
      int idx = tid + c * 256;                                                       \
      int row = idx >> 3, kc = idx & 7;                                              \
      gl_lds16(&Bt[(size_t)(ntile + row) * K + (K0) + kc * 8], &Bb_[idx * 8]);       \
    }                                                                                \
  } while (0)

  STAGE_PRJ(0, 0);
  __syncthreads();
  int cur = 0;
  for (int it = 0; it < 16; ++it) {
    if (it < 15) STAGE_PRJ(cur ^ 1, (it + 1) * 64);
    const short* Ab = smem + cur * 12288;
    const short* Bb = Ab + 8192;
    __builtin_amdgcn_s_setprio(1);
    #pragma unroll
    for (int kk = 0; kk < 2; ++kk) {
      bf16x8 af[2], bfr[4];
      #pragma unroll
      for (int i = 0; i < 2; ++i)
        af[i] = *reinterpret_cast<const bf16x8*>(&Ab[(w * 32 + i * 16 + lr) * 64 + kk * 32 + lg * 8]);
      #pragma unroll
      for (int j = 0; j < 4; ++j)
        bfr[j] = *reinterpret_cast<const bf16x8*>(&Bb[(j * 16 + lr) * 64 + kk * 32 + lg * 8]);
      #pragma unroll
      for (int i = 0; i < 2; ++i)
        #pragma unroll
        for (int j = 0; j < 4; ++j)
          acc[i][j] = __builtin_amdgcn_mfma_f32_16x16x32_bf16(af[i], bfr[j], acc[i][j], 0, 0, 0);
    }
    __builtin_amdgcn_s_setprio(0);
    __syncthreads();
    cur ^= 1;
  }
#undef STAGE_PRJ

  #pragma unroll
  for (int j = 0; j < 4; ++j) {
    int n = ntile + j * 16 + lr;
    float bv = bias[n];
    #pragma unroll
    for (int i = 0; i < 2; ++i) {
      #pragma unroll
      for (int r2 = 0; r2 < 4; ++r2) {
        int m = mtile + w * 32 + i * 16 + lg * 4 + r2;
        out[(size_t)m * 1024 + n] = acc[i][j][r2] + bv;
      }
    }
  }
}

extern "C" void kernel_launch(void* const* d_in, const int* in_sizes, int n_in,
                              void* d_out, int out_size, void* d_ws, size_t ws_size,
                              hipStream_t stream) {
  const float* x     = (const float*)d_in[0];
  const float* Wqkv  = (const float*)d_in[1];
  const float* bqkv  = (const float*)d_in[2];
  const float* Wproj = (const float*)d_in[3];
  const float* bproj = (const float*)d_in[4];
  float* out = (float*)d_out;

  const size_t M4 = 4096ull * 1024ull;
  short* ws = (short*)d_ws;
  short* x_bf    = ws;
  short* wqkv_t  = ws + M4;
  short* wproj_t = ws + M4 + 3ull * 1024 * 1024;
  short* qb      = wproj_t + 1024ull * 1024;
  short* kb      = qb + M4;
  short* vtb     = kb + M4;     // fragment-swizzled V^T
  short* yb      = x_bf;        // alias: x_bf dead after gemm_qkv

  cast_x_kernel<<<4096, 256, 0, stream>>>(x, x_bf, (int)(M4 / 4));
  transpose_cast<<<dim3(48, 16), 256, 0, stream>>>(Wqkv, wqkv_t, 1024, 3072);
  transpose_cast<<<dim3(16, 16), 256, 0, stream>>>(Wproj, wproj_t, 1024, 1024);
  gemm_qkv<<<768, 256, 0, stream>>>(x_bf, wqkv_t, bqkv, qb, kb, vtb);
  attn_kernel<<<2048, 256, 0, stream>>>(qb, kb, vtb, yb);
  gemm_proj<<<512, 256, 0, stream>>>(yb, wproj_t, bproj, out);
}